// Round 19
// baseline (599.094 us; speedup 1.0000x reference)
//
#include <hip/hip_runtime.h>
#include <math.h>

#define HIDC 128
#define NH 8
#define HD 16
#define NCLS 4

typedef __attribute__((ext_vector_type(8))) short s8v;
typedef __attribute__((ext_vector_type(4))) float f4v;

#define ST_STRIDE 264   // ushorts per staged split-bf16 row (528 B)
#define ST_BYTES  (64 * ST_STRIDE * 2)   // 33792
#define MNEG (-3.0e38f)  // finite "-inf" so empty-state merges never compute inf-inf

__device__ __forceinline__ float gelu_f(float h) {
    float z = 0.7978845608028654f * (h + 0.044715f * h * h * h);
    float t = 1.f - 2.f / (1.f + __expf(2.f * z));   // tanh(z)
    return 0.5f * h * (1.f + t);
}
__device__ __forceinline__ unsigned short f2bf(float x) {
    unsigned b = __float_as_uint(x);
    unsigned r = (b + 0x7FFFu + ((b >> 16) & 1u)) >> 16;
    return (unsigned short)r;
}
__device__ __forceinline__ float bf2f(unsigned short u) {
    return __uint_as_float(((unsigned)u) << 16);
}
__device__ __forceinline__ void gload_lds16(const void* g, void* l) {
    __builtin_amdgcn_global_load_lds(
        (const __attribute__((address_space(1))) unsigned int*)g,
        (__attribute__((address_space(3))) unsigned int*)l, 16, 0, 0);
}

__global__ void zero_u32(unsigned* __restrict__ p, long n)
{
    long i = (long)blockIdx.x * blockDim.x + threadIdx.x;
    long stride = (long)gridDim.x * blockDim.x;
    for (; i < n; i += stride) p[i] = 0u;
}

// Fold relation transforms into K/V projection weights (f32 [k][col]).
__global__ void fold_all(const float* __restrict__ Wk, const float* __restrict__ bk,
                         const float* __restrict__ Wv, const float* __restrict__ bv,
                         const float* __restrict__ arel, const float* __restrict__ mrel,
                         float* __restrict__ Wt, float* __restrict__ bt)
{
    __shared__ float rsh[NH * HD * HD];
    int bid = blockIdx.x;
    int w = bid & 1, r = (bid >> 1) & 3, l = bid >> 3;
    int st = r >> 1;
    const float* W   = (w ? Wv : Wk) + (size_t)(l * 2 + st) * HIDC * HIDC;
    const float* bb  = (w ? bv : bk) + (size_t)(l * 2 + st) * HIDC;
    const float* rel = (w ? mrel : arel) + (size_t)(l * 4 + r) * NH * HD * HD;
    float* wt  = Wt + (size_t)bid * HIDC * HIDC;
    float* btp = bt + (size_t)bid * HIDC;

    int t = threadIdx.x;
    for (int i = t; i < NH * HD * HD; i += 128) rsh[i] = rel[i];
    __syncthreads();
    int h = t >> 4, f = t & 15;
    const float* rh = rsh + h * HD * HD + f;
    for (int k = 0; k < HIDC; ++k) {
        float acc = 0.f;
        const float* wr = W + (size_t)k * HIDC + h * HD;
        #pragma unroll
        for (int d = 0; d < HD; ++d) acc = fmaf(wr[d], rh[d * HD], acc);
        wt[(size_t)k * HIDC + t] = acc;
    }
    float accb = 0.f;
    const float* br = bb + h * HD;
    #pragma unroll
    for (int d = 0; d < HD; ++d) accb = fmaf(br[d], rh[d * HD], accb);
    btp[t] = accb;
}

// Split weights to bf16 hi/lo in MFMA-tiled chunk order.
__global__ __launch_bounds__(128)
void wsplit(const float* __restrict__ linWa, const float* __restrict__ linWb,
            const float* __restrict__ Wq, const float* __restrict__ Wa,
            const float* __restrict__ Wt, unsigned short* __restrict__ W2,
            int Ka, int Kb)
{
    int bid = blockIdx.x;
    int nka = Ka >> 5, nkb = Kb >> 5;
    const float* src; size_t moff; int ks, Km;
    if (bid < nka) { src = linWa; moff = 0; ks = bid; Km = Ka; }
    else if (bid < nka + nkb) { src = linWb; moff = (size_t)2 * Ka * 128; ks = bid - nka; Km = Kb; }
    else {
        int cc = bid - nka - nkb;
        int mm = cc >> 2; ks = cc & 3; Km = 128;
        moff = (size_t)2 * (Ka + Kb) * 128 + (size_t)mm * 32768;
        if (mm < 16)      src = Wt + (size_t)mm * 16384;
        else if (mm < 20) src = Wq + (size_t)(mm - 16) * 16384;
        else              src = Wa + (size_t)(mm - 20) * 16384;
    }
    int t = threadIdx.x;
    int fn = t >> 4, lr = t & 15;
    for (int g = 0; g < 4; ++g)
        for (int j = 0; j < 8; ++j) {
            int k = ks * 32 + g * 8 + j;
            float x = src[(size_t)k * 128 + fn * 16 + lr];
            unsigned short h = f2bf(x);
            size_t co = moff + (size_t)ks * 4096 + fn * 512 + g * 128 + lr * 8 + j;
            W2[co] = h;
            W2[co + (size_t)Km * 128] = f2bf(x - bf2f(h));
        }
}

// ---- CSR build (merged over all 4 edge lists) ----
__global__ void hist4(const int* __restrict__ d0, int E0, const int* __restrict__ d1, int E1,
                      const int* __restrict__ d2, int E2, const int* __restrict__ d3, int E3,
                      unsigned* __restrict__ cnt, int Nmax)
{
    int i = blockIdx.x * blockDim.x + threadIdx.x;
    int tot = E0 + E1 + E2 + E3;
    int stride = gridDim.x * blockDim.x;
    for (; i < tot; i += stride) {
        int j = i; const int* p; int dt;
        if (j < E0) { p = d0; dt = 0; }
        else { j -= E0;
            if (j < E1) { p = d1; dt = 1; }
            else { j -= E1;
                if (j < E2) { p = d2; dt = 0; }
                else { j -= E2; p = d3; dt = 1; }
            }
        }
        atomicAdd(&cnt[(size_t)dt * Nmax + p[j]], 1u);
    }
}

__global__ __launch_bounds__(256)
void scan_p1(const unsigned* __restrict__ cnt, unsigned* __restrict__ bsum,
             int Nmax, int nblk, int n0, int n1)
{
    int ty = blockIdx.x / nblk, b = blockIdx.x % nblk;
    int n = ty ? n1 : n0;
    const unsigned* c = cnt + (size_t)ty * Nmax;
    int i0 = b * 1024 + threadIdx.x * 4;
    unsigned s = 0;
    #pragma unroll
    for (int j = 0; j < 4; ++j) { int i = i0 + j; if (i < n) s += c[i]; }
    __shared__ unsigned sh[256];
    sh[threadIdx.x] = s; __syncthreads();
    for (int off = 128; off; off >>= 1) {
        if (threadIdx.x < (unsigned)off) sh[threadIdx.x] += sh[threadIdx.x + off];
        __syncthreads();
    }
    if (threadIdx.x == 0) bsum[blockIdx.x] = sh[0];
}

__global__ __launch_bounds__(256)
void scan_p2(unsigned* __restrict__ bsum, int nblk, int* __restrict__ rowptr,
             int Nmax, int n0, int n1)
{
    __shared__ unsigned sh[256];
    int tot = 2 * nblk;
    int t = threadIdx.x;
    unsigned v = (t < tot) ? bsum[t] : 0u;
    sh[t] = v; __syncthreads();
    for (int off = 1; off < 256; off <<= 1) {
        unsigned add = (t >= off) ? sh[t - off] : 0u;
        __syncthreads(); sh[t] += add; __syncthreads();
    }
    unsigned t0 = sh[nblk - 1];
    unsigned tall = sh[255];
    unsigned excl = sh[t] - v;
    if (t < tot) bsum[t] = (t < nblk) ? excl : excl - t0;
    if (t == 0) {
        rowptr[n0] = (int)t0;
        rowptr[(Nmax + 1) + n1] = (int)(tall - t0);
    }
}

__global__ __launch_bounds__(256)
void scan_p3(const unsigned* __restrict__ cnt, const unsigned* __restrict__ bsum,
             int* __restrict__ rowptr, unsigned* __restrict__ cursor,
             int Nmax, int nblk, int n0, int n1)
{
    int ty = blockIdx.x / nblk, b = blockIdx.x % nblk;
    int n = ty ? n1 : n0;
    const unsigned* c = cnt + (size_t)ty * Nmax;
    int* rp = rowptr + (size_t)ty * (Nmax + 1);
    unsigned* cur = cursor + (size_t)ty * Nmax;
    int t = threadIdx.x;
    int i0 = b * 1024 + t * 4;
    unsigned v[4]; unsigned s = 0;
    #pragma unroll
    for (int j = 0; j < 4; ++j) { int i = i0 + j; v[j] = (i < n) ? c[i] : 0u; s += v[j]; }
    __shared__ unsigned sh[256];
    sh[t] = s; __syncthreads();
    for (int off = 1; off < 256; off <<= 1) {
        unsigned add = (t >= off) ? sh[t - off] : 0u;
        __syncthreads(); sh[t] += add; __syncthreads();
    }
    unsigned run = bsum[blockIdx.x] + sh[t] - s;
    #pragma unroll
    for (int j = 0; j < 4; ++j) {
        int i = i0 + j;
        if (i < n) { rp[i] = (int)run; cur[i] = run; }
        run += v[j];
    }
}

__global__ void scatter4(const int* __restrict__ e0, int E0, const int* __restrict__ e1, int E1,
                         const int* __restrict__ e2, int E2, const int* __restrict__ e3, int E3,
                         unsigned* __restrict__ cursor, int Nmax,
                         unsigned* __restrict__ adj0, unsigned* __restrict__ adj1)
{
    int i = blockIdx.x * blockDim.x + threadIdx.x;
    int tot = E0 + E1 + E2 + E3;
    int stride = gridDim.x * blockDim.x;
    for (; i < tot; i += stride) {
        int j = i; const int* e; int E; int dt; unsigned rb;
        if (j < E0) { e = e0; E = E0; dt = 0; rb = 0u; }
        else { j -= E0;
            if (j < E1) { e = e1; E = E1; dt = 1; rb = 0u; }
            else { j -= E1;
                if (j < E2) { e = e2; E = E2; dt = 0; rb = 1u << 24; }
                else { j -= E2; e = e3; E = E3; dt = 1; rb = 1u << 24; }
            }
        }
        int s = e[j], d = e[E + j];
        unsigned pos = atomicAdd(&cursor[(size_t)dt * Nmax + d], 1u);
        (dt ? adj1 : adj0)[pos] = (unsigned)s | rb;
    }
}

// ---- single-pass 2-product MFMA GEMM, 64-row tile, 256 thr ----
template <int ASPLIT, int EPI, int OUT, int NK>
__global__ __launch_bounds__(256)
void mg2p(const void* __restrict__ Ain, const unsigned short* __restrict__ Whi,
          const float* __restrict__ bias,
          const unsigned short* __restrict__ xold, const float* __restrict__ skipp,
          void* __restrict__ Cout, int N)
{
    constexpr int K = NK * 32;
    constexpr int PB = NK * 8192;
    constexpr size_t LSZ = (OUT == 2 && ST_BYTES > PB) ? ST_BYTES : PB;
    __shared__ char ldsraw[LSZ];
    unsigned short* lds = (unsigned short*)ldsraw;
    int t = threadIdx.x;
    constexpr int NCP = PB / (16 * 256);
    #pragma unroll
    for (int i = 0; i < NCP; ++i)
        gload_lds16((const char*)Whi + ((size_t)t + i * 256) * 16,
                    ldsraw + ((size_t)t + i * 256) * 16);
    __syncthreads();

    int w = t >> 6, lane = t & 63;
    int lr = lane & 15, g = lane >> 4;
    int row0 = blockIdx.x * 64;
    int fnb = w * 2;

    f4v acc[4][2];
    #pragma unroll
    for (int i = 0; i < 4; ++i) { acc[i][0] = (f4v)0.f; acc[i][1] = (f4v)0.f; }

    #pragma unroll
    for (int ks = 0; ks < NK; ++ks) {
        s8v ah[4], al[4];
        #pragma unroll
        for (int fm = 0; fm < 4; ++fm) {
            int row = row0 + fm * 16 + lr;
            if (row < N) {
                if (ASPLIT) {
                    const unsigned short* ap = (const unsigned short*)Ain + (size_t)row * 256 + ks * 32 + g * 8;
                    ah[fm] = *(const s8v*)ap;
                    al[fm] = *(const s8v*)(ap + 128);
                } else {
                    const float* ap = (const float*)Ain + (size_t)row * K + ks * 32 + g * 8;
                    float4 p = *(const float4*)ap;
                    float4 q = *(const float4*)(ap + 4);
                    float xv[8] = {p.x, p.y, p.z, p.w, q.x, q.y, q.z, q.w};
                    #pragma unroll
                    for (int j = 0; j < 8; ++j) {
                        unsigned short h = f2bf(xv[j]);
                        ah[fm][j] = (short)h;
                        al[fm][j] = (short)f2bf(xv[j] - bf2f(h));
                    }
                }
            } else { ah[fm] = (s8v)0; al[fm] = (s8v)0; }
        }
        #pragma unroll
        for (int f = 0; f < 2; ++f) {
            size_t co = (size_t)ks * 8192 + (fnb + f) * 1024 + g * 256 + lr * 16;
            s8v b = *(const s8v*)(ldsraw + co);
            #pragma unroll
            for (int fm = 0; fm < 4; ++fm) {
                acc[fm][f] = __builtin_amdgcn_mfma_f32_16x16x32_bf16(ah[fm], b, acc[fm][f], 0, 0, 0);
                acc[fm][f] = __builtin_amdgcn_mfma_f32_16x16x32_bf16(al[fm], b, acc[fm][f], 0, 0, 0);
            }
        }
    }

    float beta = 0.f;
    if (EPI == 2) beta = 1.f / (1.f + __expf(-skipp[0]));
    int rb = g * 4;

    if (OUT == 2) {
        __syncthreads();
        #pragma unroll
        for (int f = 0; f < 2; ++f) {
            int col = (fnb + f) * 16 + lr;
            float bv = bias[col];
            #pragma unroll
            for (int fm = 0; fm < 4; ++fm) {
                #pragma unroll
                for (int j = 0; j < 4; ++j) {
                    int lrow = fm * 16 + rb + j;
                    int row = row0 + lrow;
                    float o = acc[fm][f][j] + bv;
                    if (EPI == 1) o = fmaxf(o, 0.f);
                    if (EPI == 2) {
                        float xo = (row < N) ? (bf2f(xold[(size_t)row * 256 + col]) +
                                                bf2f(xold[(size_t)row * 256 + 128 + col])) : 0.f;
                        o = beta * o + (1.f - beta) * xo;
                    }
                    unsigned short h = f2bf(o);
                    lds[(size_t)lrow * ST_STRIDE + col] = h;
                    lds[(size_t)lrow * ST_STRIDE + 128 + col] = f2bf(o - bf2f(h));
                }
            }
        }
        __syncthreads();
        unsigned short* C = (unsigned short*)Cout;
        #pragma unroll
        for (int it = 0; it < 8; ++it) {
            int d4 = (it * 256 + t) * 4;
            int row = d4 >> 7, c2 = d4 & 127;
            int grow = row0 + row;
            if (grow < N) {
                uint4 v = *(const uint4*)(lds + (size_t)row * ST_STRIDE + c2 * 2);
                *(uint4*)(C + (size_t)grow * 256 + c2 * 2) = v;
            }
        }
    } else {
        float* C = (float*)Cout;
        #pragma unroll
        for (int f = 0; f < 2; ++f) {
            int col = (fnb + f) * 16 + lr;
            float bv = bias[col];
            #pragma unroll
            for (int fm = 0; fm < 4; ++fm) {
                #pragma unroll
                for (int j = 0; j < 4; ++j) {
                    int row = row0 + fm * 16 + rb + j;
                    if (row < N) C[(size_t)row * HIDC + col] = acc[fm][f][j] + bv;
                }
            }
        }
    }
}

// ---- batched dual kv GEMM: 4 jobs (st,dt), 64-row tile, 2-product ----
struct KvArgs {
    const unsigned short* A[4];
    const unsigned short* Wm[4];
    const float* bias[4];
    unsigned short* out[4];
    int N[4];
    int cum[5];
};

__global__ __launch_bounds__(256)
void mgemm_kv4(KvArgs args)
{
    int bid = blockIdx.x;
    int jb = 0;
    while (jb < 3 && bid >= args.cum[jb + 1]) ++jb;
    int lb = bid - args.cum[jb];
    const unsigned short* Ain = args.A[jb];
    const unsigned short* Wkt = args.Wm[jb];
    const unsigned short* Wvt = args.Wm[jb] + 32768;
    const float* bias2 = args.bias[jb];
    unsigned short* kv = args.out[jb];
    int N = args.N[jb];

    __shared__ char ldsraw[65536];
    unsigned short* lds = (unsigned short*)ldsraw;
    int t = threadIdx.x;
    #pragma unroll
    for (int i = 0; i < 8; ++i)
        gload_lds16((const char*)Wkt + ((size_t)t + i * 256) * 16,
                    ldsraw + ((size_t)t + i * 256) * 16);
    #pragma unroll
    for (int i = 0; i < 8; ++i)
        gload_lds16((const char*)Wvt + ((size_t)t + i * 256) * 16,
                    ldsraw + 32768 + ((size_t)t + i * 256) * 16);

    int w = t >> 6, lane = t & 63;
    int lr = lane & 15, g = lane >> 4;
    int row0 = lb * 64;
    int fnb = w * 2;

    s8v ah[4][4], al[4][4];
    #pragma unroll
    for (int fm = 0; fm < 4; ++fm) {
        int row = row0 + fm * 16 + lr;
        #pragma unroll
        for (int ks = 0; ks < 4; ++ks) {
            if (row < N) {
                const unsigned short* ap = Ain + (size_t)row * 256 + ks * 32 + g * 8;
                ah[fm][ks] = *(const s8v*)ap;
                al[fm][ks] = *(const s8v*)(ap + 128);
            } else { ah[fm][ks] = (s8v)0; al[fm][ks] = (s8v)0; }
        }
    }
    __syncthreads();

    f4v acck[4][2], accv[4][2];
    #pragma unroll
    for (int i = 0; i < 4; ++i) {
        acck[i][0] = (f4v)0.f; acck[i][1] = (f4v)0.f;
        accv[i][0] = (f4v)0.f; accv[i][1] = (f4v)0.f;
    }

    #pragma unroll
    for (int ks = 0; ks < 4; ++ks) {
        #pragma unroll
        for (int f = 0; f < 2; ++f) {
            int fn = fnb + f;
            size_t co = (size_t)ks * 8192 + fn * 1024 + g * 256 + lr * 16;
            s8v bk_ = *(const s8v*)(ldsraw + co);
            s8v bv_ = *(const s8v*)(ldsraw + 32768 + co);
            #pragma unroll
            for (int fm = 0; fm < 4; ++fm) {
                acck[fm][f] = __builtin_amdgcn_mfma_f32_16x16x32_bf16(ah[fm][ks], bk_, acck[fm][f], 0, 0, 0);
                acck[fm][f] = __builtin_amdgcn_mfma_f32_16x16x32_bf16(al[fm][ks], bk_, acck[fm][f], 0, 0, 0);
                accv[fm][f] = __builtin_amdgcn_mfma_f32_16x16x32_bf16(ah[fm][ks], bv_, accv[fm][f], 0, 0, 0);
                accv[fm][f] = __builtin_amdgcn_mfma_f32_16x16x32_bf16(al[fm][ks], bv_, accv[fm][f], 0, 0, 0);
            }
        }
    }

    __syncthreads();
    int rb = g * 4;
    #pragma unroll
    for (int f = 0; f < 2; ++f) {
        int fn = fnb + f;
        int col = fn * 16 + lr;
        float bk0 = bias2[col], bv0 = bias2[128 + col];
        #pragma unroll
        for (int fm = 0; fm < 4; ++fm) {
            #pragma unroll
            for (int j = 0; j < 4; ++j) {
                int lrow = fm * 16 + rb + j;
                lds[(size_t)lrow * ST_STRIDE + col] = f2bf(acck[fm][f][j] + bk0);
                lds[(size_t)lrow * ST_STRIDE + 128 + col] = f2bf(accv[fm][f][j] + bv0);
            }
        }
    }
    __syncthreads();
    #pragma unroll
    for (int it = 0; it < 8; ++it) {
        int d4 = (it * 256 + t) * 4;
        int row = d4 >> 7, c2 = d4 & 127;
        int grow = row0 + row;
        if (grow < N) {
            uint4 v = *(const uint4*)(lds + (size_t)row * ST_STRIDE + c2 * 2);
            *(uint4*)(kv + (size_t)grow * 256 + c2 * 2) = v;
        }
    }
}

// ---- batched q GEMM: 2 jobs, 64-row tile, 2-product, f32 out ----
struct QArgs {
    const unsigned short* A[2];
    const unsigned short* W[2];
    const float* bias[2];
    float* out[2];
    int N[2];
    int cum[3];
};

__global__ __launch_bounds__(256)
void mgemm_q2(QArgs args)
{
    int bid = blockIdx.x;
    int jb = (bid >= args.cum[1]) ? 1 : 0;
    int lb = bid - args.cum[jb];
    const unsigned short* Ain = args.A[jb];
    const unsigned short* Whi = args.W[jb];
    const float* bias = args.bias[jb];
    float* Cout = args.out[jb];
    int N = args.N[jb];

    __shared__ char ldsraw[32768];
    int t = threadIdx.x;
    #pragma unroll
    for (int i = 0; i < 8; ++i)
        gload_lds16((const char*)Whi + ((size_t)t + i * 256) * 16,
                    ldsraw + ((size_t)t + i * 256) * 16);
    __syncthreads();

    int w = t >> 6, lane = t & 63;
    int lr = lane & 15, g = lane >> 4;
    int row0 = lb * 64;
    int fnb = w * 2;

    f4v acc[4][2];
    #pragma unroll
    for (int i = 0; i < 4; ++i) { acc[i][0] = (f4v)0.f; acc[i][1] = (f4v)0.f; }

    #pragma unroll
    for (int ks = 0; ks < 4; ++ks) {
        s8v ah[4], al[4];
        #pragma unroll
        for (int fm = 0; fm < 4; ++fm) {
            int row = row0 + fm * 16 + lr;
            if (row < N) {
                const unsigned short* ap = Ain + (size_t)row * 256 + ks * 32 + g * 8;
                ah[fm] = *(const s8v*)ap;
                al[fm] = *(const s8v*)(ap + 128);
            } else { ah[fm] = (s8v)0; al[fm] = (s8v)0; }
        }
        #pragma unroll
        for (int f = 0; f < 2; ++f) {
            size_t co = (size_t)ks * 8192 + (fnb + f) * 1024 + g * 256 + lr * 16;
            s8v b = *(const s8v*)(ldsraw + co);
            #pragma unroll
            for (int fm = 0; fm < 4; ++fm) {
                acc[fm][f] = __builtin_amdgcn_mfma_f32_16x16x32_bf16(ah[fm], b, acc[fm][f], 0, 0, 0);
                acc[fm][f] = __builtin_amdgcn_mfma_f32_16x16x32_bf16(al[fm], b, acc[fm][f], 0, 0, 0);
            }
        }
    }

    int rb = g * 4;
    #pragma unroll
    for (int f = 0; f < 2; ++f) {
        int col = (fnb + f) * 16 + lr;
        float bv = bias[col];
        #pragma unroll
        for (int fm = 0; fm < 4; ++fm) {
            #pragma unroll
            for (int j = 0; j < 4; ++j) {
                int row = row0 + fm * 16 + rb + j;
                if (row < N) Cout[(size_t)row * HIDC + col] = acc[fm][f][j] + bv;
            }
        }
    }
}

// ---- batched outproj GEMM: 2 jobs, 64-row tile, 2-product, skip-blend, in-place ----
struct OArgs {
    const unsigned short* A[2];
    const unsigned short* W[2];
    const float* bias[2];
    const float* skipp[2];
    unsigned short* x[2];
    int N[2];
    int cum[3];
};

__global__ __launch_bounds__(256)
void mgemm_op2(OArgs args)
{
    int bid = blockIdx.x;
    int jb = (bid >= args.cum[1]) ? 1 : 0;
    int lb = bid - args.cum[jb];
    const unsigned short* Ain = args.A[jb];
    const unsigned short* Whi = args.W[jb];
    const float* bias = args.bias[jb];
    const unsigned short* xold = args.x[jb];
    unsigned short* Cout = args.x[jb];
    float beta = 1.f / (1.f + __expf(-args.skipp[jb][0]));
    int N = args.N[jb];

    __shared__ char ldsraw[ST_BYTES];
    unsigned short* lds = (unsigned short*)ldsraw;
    int t = threadIdx.x;
    #pragma unroll
    for (int i = 0; i < 8; ++i)
        gload_lds16((const char*)Whi + ((size_t)t + i * 256) * 16,
                    ldsraw + ((size_t)t + i * 256) * 16);
    __syncthreads();

    int w = t >> 6, lane = t & 63;
    int lr = lane & 15, g = lane >> 4;
    int row0 = lb * 64;
    int fnb = w * 2;

    f4v acc[4][2];
    #pragma unroll
    for (int i = 0; i < 4; ++i) { acc[i][0] = (f4v)0.f; acc[i][1] = (f4v)0.f; }

    #pragma unroll
    for (int ks = 0; ks < 4; ++ks) {
        s8v ah[4], al[4];
        #pragma unroll
        for (int fm = 0; fm < 4; ++fm) {
            int row = row0 + fm * 16 + lr;
            if (row < N) {
                const unsigned short* ap = Ain + (size_t)row * 256 + ks * 32 + g * 8;
                ah[fm] = *(const s8v*)ap;
                al[fm] = *(const s8v*)(ap + 128);
            } else { ah[fm] = (s8v)0; al[fm] = (s8v)0; }
        }
        #pragma unroll
        for (int f = 0; f < 2; ++f) {
            size_t co = (size_t)ks * 8192 + (fnb + f) * 1024 + g * 256 + lr * 16;
            s8v b = *(const s8v*)(ldsraw + co);
            #pragma unroll
            for (int fm = 0; fm < 4; ++fm) {
                acc[fm][f] = __builtin_amdgcn_mfma_f32_16x16x32_bf16(ah[fm], b, acc[fm][f], 0, 0, 0);
                acc[fm][f] = __builtin_amdgcn_mfma_f32_16x16x32_bf16(al[fm], b, acc[fm][f], 0, 0, 0);
            }
        }
    }

    int rb = g * 4;
    __syncthreads();
    #pragma unroll
    for (int f = 0; f < 2; ++f) {
        int col = (fnb + f) * 16 + lr;
        float bv = bias[col];
        #pragma unroll
        for (int fm = 0; fm < 4; ++fm) {
            #pragma unroll
            for (int j = 0; j < 4; ++j) {
                int lrow = fm * 16 + rb + j;
                int row = row0 + lrow;
                float o = acc[fm][f][j] + bv;
                float xo = (row < N) ? (bf2f(xold[(size_t)row * 256 + col]) +
                                        bf2f(xold[(size_t)row * 256 + 128 + col])) : 0.f;
                o = beta * o + (1.f - beta) * xo;
                unsigned short h = f2bf(o);
                lds[(size_t)lrow * ST_STRIDE + col] = h;
                lds[(size_t)lrow * ST_STRIDE + 128 + col] = f2bf(o - bf2f(h));
            }
        }
    }
    __syncthreads();
    #pragma unroll
    for (int it = 0; it < 8; ++it) {
        int d4 = (it * 256 + t) * 4;
        int row = d4 >> 7, c2 = d4 & 127;
        int grow = row0 + row;
        if (grow < N) {
            uint4 v = *(const uint4*)(lds + (size_t)row * ST_STRIDE + c2 * 2);
            *(uint4*)(Cout + (size_t)grow * 256 + c2 * 2) = v;
        }
    }
}

// ---- batched fused aggregation: 2 jobs (dt 0/1); 2 edges per wave, 4 dims/lane ----
struct AArgs {
    const float* Q[2];
    const unsigned short* kvA_[2];
    const unsigned short* kvB_[2];
    const int* rowptr[2];
    const unsigned* adjp[2];
    const float* prelA_[2];
    const float* prelB_[2];
    unsigned short* out[2];   // aliases Q (same buffer reinterpreted)
    int N[2];
    int cum[3];
};

__global__ __launch_bounds__(256)
void agg2(AArgs args, float scale)
{
    int bid = blockIdx.x;
    int jb = (bid >= args.cum[1]) ? 1 : 0;
    int lb = bid - args.cum[jb];
    const float* Q = args.Q[jb];
    const unsigned short* kvA = args.kvA_[jb];
    const unsigned short* kvB = args.kvB_[jb];
    const int* rowptr = args.rowptr[jb];
    const unsigned* adj = args.adjp[jb];
    unsigned short* msgs = args.out[jb];
    int N = args.N[jb];

    int node = lb * 4 + (threadIdx.x >> 6);
    if (node >= N) return;
    int lane = threadIdx.x & 63;
    int e2 = lane >> 5;
    int sub = lane & 31;
    int h = sub >> 2;
    int off = h * 16 + (sub & 3) * 4;
    float spA = args.prelA_[jb][h] * scale, spB = args.prelB_[jb][h] * scale;

    float4 qv = *(const float4*)(Q + (size_t)node * HIDC + off);
    int beg = rowptr[node], end = rowptr[node + 1];

    float m0 = MNEG, s0 = 0.f, v00 = 0.f, v01 = 0.f, v02 = 0.f, v03 = 0.f;
    float m1 = MNEG, s1 = 0.f, v10 = 0.f, v11 = 0.f, v12 = 0.f, v13 = 0.f;

#define ESTEP(I, M, S, A0, A1, A2, A3)                                            \
    {                                                                             \
        int ei = (I) + e2;                                                        \
        bool valid = ei < end;                                                    \
        unsigned ent = valid ? adj[ei] : 0u;                                      \
        int src = (int)(ent & 0xFFFFFFu);                                         \
        const unsigned short* kvp = (ent >> 24) ? kvB : kvA;                      \
        float sp = (ent >> 24) ? spB : spA;                                       \
        ushort4 kr = *(const ushort4*)(kvp + (size_t)src * 256 + off);            \
        ushort4 vr = *(const ushort4*)(kvp + (size_t)src * 256 + 128 + off);      \
        float p = bf2f(kr.x) * qv.x + bf2f(kr.y) * qv.y +                         \
                  bf2f(kr.z) * qv.z + bf2f(kr.w) * qv.w;                          \
        p += __shfl_xor(p, 1, 4);                                                 \
        p += __shfl_xor(p, 2, 4);                                                 \
        float a = p * sp;                                                         \
        float d = a - M;                                                          \
        float e = __expf(-fabsf(d));                                              \
        bool nm = valid && (d > 0.f);                                             \
        float sc = nm ? e : 1.f;                                                  \
        float pw = nm ? 1.f : e;                                                  \
        pw = valid ? pw : 0.f;                                                    \
        S = S * sc + pw;                                                          \
        A0 = A0 * sc + pw * bf2f(vr.x);                                           \
        A1 = A1 * sc + pw * bf2f(vr.y);                                           \
        A2 = A2 * sc + pw * bf2f(vr.z);                                           \
        A3 = A3 * sc + pw * bf2f(vr.w);                                           \
        M = nm ? a : M;                                                           \
    }

    int i = beg;
    for (; i + 3 < end; i += 4) {
        ESTEP(i,     m0, s0, v00, v01, v02, v03);
        ESTEP(i + 2, m1, s1, v10, v11, v12, v13);
    }
    if (i < end) { ESTEP(i, m0, s0, v00, v01, v02, v03); i += 2; }
    if (i < end) { ESTEP(i, m1, s1, v10, v11, v12, v13); }

    float o0 = 0.f, o1 = 0.f, o2 = 0.f, o3 = 0.f;
    if (end > beg) {
        // in-lane state merge; empty state (m=MNEG) gives exp(<=0) weight on s=0 -> harmless
        float mm = fmaxf(m0, m1);
        float c0 = __expf(m0 - mm), c1 = __expf(m1 - mm);
        float ss = s0 * c0 + s1 * c1;
        float b0 = v00 * c0 + v10 * c1;
        float b1 = v01 * c0 + v11 * c1;
        float b2 = v02 * c0 + v12 * c1;
        float b3 = v03 * c0 + v13 * c1;
        // merge halves (lane ^ 32)
        float om = __shfl_xor(mm, 32);
        float os = __shfl_xor(ss, 32);
        float ob0 = __shfl_xor(b0, 32);
        float ob1 = __shfl_xor(b1, 32);
        float ob2 = __shfl_xor(b2, 32);
        float ob3 = __shfl_xor(b3, 32);
        float mn = fmaxf(mm, om);
        float d0 = __expf(mm - mn), d1 = __expf(om - mn);
        float s = ss * d0 + os * d1;
        float inv = 1.f / fmaxf(s, 1e-16f);
        o0 = (b0 * d0 + ob0 * d1) * inv;
        o1 = (b1 * d0 + ob1 * d1) * inv;
        o2 = (b2 * d0 + ob2 * d1) * inv;
        o3 = (b3 * d0 + ob3 * d1) * inv;
    }
    o0 = gelu_f(o0); o1 = gelu_f(o1); o2 = gelu_f(o2); o3 = gelu_f(o3);
    if (e2 == 0) {
        ushort4 hi, lo;
        hi.x = f2bf(o0); lo.x = f2bf(o0 - bf2f(hi.x));
        hi.y = f2bf(o1); lo.y = f2bf(o1 - bf2f(hi.y));
        hi.z = f2bf(o2); lo.z = f2bf(o2 - bf2f(hi.z));
        hi.w = f2bf(o3); lo.w = f2bf(o3 - bf2f(hi.w));
        *(ushort4*)(msgs + (size_t)node * 256 + off) = hi;
        *(ushort4*)(msgs + (size_t)node * 256 + 128 + off) = lo;
    }
#undef ESTEP
}

// ---- classifier: one wave per row, x split-bf16 ----
__global__ __launch_bounds__(256)
void cls_kernel(const unsigned short* __restrict__ X, const float* __restrict__ Wc,
                const float* __restrict__ bc, float* __restrict__ out, int N)
{
    int row = blockIdx.x * 4 + (threadIdx.x >> 6);
    if (row >= N) return;
    int lane = threadIdx.x & 63;
    const unsigned short* xr = X + (size_t)row * 256 + lane * 2;
    float x0 = bf2f(xr[0]) + bf2f(xr[128]);
    float x1 = bf2f(xr[1]) + bf2f(xr[129]);
    float p0, p1, p2, p3;
    {
        float2 w0 = *(const float2*)(Wc + 0 * HIDC + lane * 2);
        float2 w1 = *(const float2*)(Wc + 1 * HIDC + lane * 2);
        float2 w2 = *(const float2*)(Wc + 2 * HIDC + lane * 2);
        float2 w3 = *(const float2*)(Wc + 3 * HIDC + lane * 2);
        p0 = x0 * w0.x + x1 * w0.y;
        p1 = x0 * w1.x + x1 * w1.y;
        p2 = x0 * w2.x + x1 * w2.y;
        p3 = x0 * w3.x + x1 * w3.y;
    }
    #pragma unroll
    for (int off = 32; off; off >>= 1) {
        p0 += __shfl_xor(p0, off);
        p1 += __shfl_xor(p1, off);
        p2 += __shfl_xor(p2, off);
        p3 += __shfl_xor(p3, off);
    }
    if (lane < 4) {
        float v = (lane == 0) ? p0 : (lane == 1) ? p1 : (lane == 2) ? p2 : p3;
        out[(size_t)row * NCLS + lane] = v + bc[lane];
    }
}

extern "C" void kernel_launch(void* const* d_in, const int* in_sizes, int n_in,
                              void* d_out, int out_size, void* d_ws, size_t ws_size,
                              hipStream_t stream)
{
    const float* x_a    = (const float*)d_in[0];
    const float* x_b    = (const float*)d_in[1];
    const float* lin_W_a= (const float*)d_in[2];
    const float* lin_b_a= (const float*)d_in[3];
    const float* lin_W_b= (const float*)d_in[4];
    const float* lin_b_b= (const float*)d_in[5];
    const float* Wk     = (const float*)d_in[6];
    const float* bk     = (const float*)d_in[7];
    const float* Wq     = (const float*)d_in[8];
    const float* bq     = (const float*)d_in[9];
    const float* Wv     = (const float*)d_in[10];
    const float* bv     = (const float*)d_in[11];
    const float* arel   = (const float*)d_in[12];
    const float* mrel   = (const float*)d_in[13];
    const float* prel   = (const float*)d_in[14];
    const float* Wa     = (const float*)d_in[15];
    const float* ba     = (const float*)d_in[16];
    const float* skip   = (const float*)d_in[17];
    const float* Wcls   = (const float*)d_in[18];
    const float* bcls   = (const float*)d_in[19];
    const int* eptr[4] = {(const int*)d_in[20], (const int*)d_in[21],
                          (const int*)d_in[22], (const int*)d_in[23]};
    int Ee[4] = {in_sizes[20] / 2, in_sizes[21] / 2, in_sizes[22] / 2, in_sizes[23] / 2};

    int Ka = in_sizes[2] / HIDC;     // 64
    int Kb = in_sizes[4] / HIDC;     // 32
    int Na = in_sizes[0] / Ka;
    int Nb = in_sizes[1] / Kb;
    int Nn[2] = {Na, Nb};
    int Nmax = Na > Nb ? Na : Nb;

    // ---- workspace layout (~212 MB) ----
    char* base = (char*)d_ws;
    unsigned short* xs[2];
    xs[0] = (unsigned short*)base; base += (size_t)Na * 256 * 2;
    xs[1] = (unsigned short*)base; base += (size_t)Nb * 256 * 2;
    float* qb[2];            // q f32; after agg, reused as split-bf16 msgs
    qb[0] = (float*)base; base += (size_t)Na * HIDC * 4;
    qb[1] = (float*)base; base += (size_t)Nb * HIDC * 4;
    unsigned short* kvb[2][2];
    for (int s = 0; s < 2; ++s)
        for (int d = 0; d < 2; ++d) { kvb[s][d] = (unsigned short*)base; base += (size_t)Nn[s] * 256 * 2; }
    float* Wt = (float*)base; base += (size_t)16 * HIDC * HIDC * 4;
    float* bt = (float*)base; base += (size_t)16 * HIDC * 4;
    size_t nW2 = (size_t)2 * (Ka + Kb) * 128 + (size_t)24 * 32768;  // ushorts
    unsigned short* W2 = (unsigned short*)base; base += nW2 * 2;
    unsigned* cnt = (unsigned*)base; base += (size_t)2 * Nmax * 4;
    unsigned* cursor = (unsigned*)base; base += (size_t)2 * Nmax * 4;
    unsigned* bsum = (unsigned*)base; base += 256 * 4;
    int* rowptr = (int*)base; base += (size_t)2 * (Nmax + 1) * 4;
    unsigned* adj0 = (unsigned*)base; base += (size_t)(Ee[0] + Ee[2]) * 4;
    unsigned* adj1 = (unsigned*)base; base += (size_t)(Ee[1] + Ee[3]) * 4;

    // W2 mat offsets (ushorts)
    size_t off_lina = 0;
    size_t off_linb = (size_t)2 * Ka * 128;
    size_t base128  = (size_t)2 * (Ka + Kb) * 128;
    auto offKT = [&](int l, int st, int dt) { return base128 + (size_t)(l * 8 + (st * 2 + dt) * 2) * 32768; };
    auto offQ  = [&](int l, int tt) { return base128 + (size_t)(16 + l * 2 + tt) * 32768; };
    auto offA  = [&](int l, int tt) { return base128 + (size_t)(20 + l * 2 + tt) * 32768; };

    // ---- weight prep ----
    fold_all<<<16, 128, 0, stream>>>(Wk, bk, Wv, bv, arel, mrel, Wt, bt);
    int nwblk = (Ka >> 5) + (Kb >> 5) + 24 * 4;
    wsplit<<<nwblk, 128, 0, stream>>>(lin_W_a, lin_W_b, Wq, Wa, Wt, W2, Ka, Kb);

    // ---- CSR build ----
    int nblk = (Nmax + 1023) / 1024;
    zero_u32<<<512, 256, 0, stream>>>(cnt, (long)2 * Nmax);
    hist4<<<1024, 256, 0, stream>>>(eptr[0] + Ee[0], Ee[0], eptr[1] + Ee[1], Ee[1],
                                    eptr[2] + Ee[2], Ee[2], eptr[3] + Ee[3], Ee[3],
                                    cnt, Nmax);
    scan_p1<<<2 * nblk, 256, 0, stream>>>(cnt, bsum, Nmax, nblk, Na, Nb);
    scan_p2<<<1, 256, 0, stream>>>(bsum, nblk, rowptr, Nmax, Na, Nb);
    scan_p3<<<2 * nblk, 256, 0, stream>>>(cnt, bsum, rowptr, cursor, Nmax, nblk, Na, Nb);
    scatter4<<<1024, 256, 0, stream>>>(eptr[0], Ee[0], eptr[1], Ee[1],
                                       eptr[2], Ee[2], eptr[3], Ee[3],
                                       cursor, Nmax, adj0, adj1);

    // ---- input projections + ReLU -> split-bf16 x ----
    int gn64[2] = {(Na + 63) / 64, (Nb + 63) / 64};
    mg2p<0, 1, 2, 2><<<gn64[0], 256, 0, stream>>>(x_a, W2 + off_lina, lin_b_a,
                                                  nullptr, nullptr, xs[0], Na);
    mg2p<0, 1, 2, 1><<<gn64[1], 256, 0, stream>>>(x_b, W2 + off_linb, lin_b_b,
                                                  nullptr, nullptr, xs[1], Nb);

    const float scale = 0.25f;   // 1/sqrt(16)
    int ganode[2] = {(Na + 3) / 4, (Nb + 3) / 4};

    for (int l = 0; l < 2; ++l) {
        KvArgs ka;
        int cum = 0;
        for (int j = 0; j < 4; ++j) {
            int st = j >> 1, dt = j & 1;
            int bid = l * 8 + (st * 2 + dt) * 2;
            ka.A[j] = xs[st];
            ka.Wm[j] = W2 + offKT(l, st, dt);
            ka.bias[j] = bt + (size_t)bid * HIDC;
            ka.out[j] = kvb[st][dt];
            ka.N[j] = Nn[st];
            ka.cum[j] = cum;
            cum += gn64[st];
        }
        ka.cum[4] = cum;
        mgemm_kv4<<<cum, 256, 0, stream>>>(ka);

        QArgs qa;
        for (int j = 0; j < 2; ++j) {
            qa.A[j] = xs[j];
            qa.W[j] = W2 + offQ(l, j);
            qa.bias[j] = bq + (l * 2 + j) * HIDC;
            qa.out[j] = qb[j];
            qa.N[j] = Nn[j];
        }
        qa.cum[0] = 0; qa.cum[1] = gn64[0]; qa.cum[2] = gn64[0] + gn64[1];
        mgemm_q2<<<qa.cum[2], 256, 0, stream>>>(qa);

        AArgs aa;
        aa.Q[0] = qb[0]; aa.Q[1] = qb[1];
        aa.kvA_[0] = kvb[0][0]; aa.kvB_[0] = kvb[1][0];
        aa.kvA_[1] = kvb[0][1]; aa.kvB_[1] = kvb[1][1];
        aa.rowptr[0] = rowptr; aa.rowptr[1] = rowptr + (Nmax + 1);
        aa.adjp[0] = adj0; aa.adjp[1] = adj1;
        aa.prelA_[0] = prel + (l * 4 + 0) * NH; aa.prelB_[0] = prel + (l * 4 + 2) * NH;
        aa.prelA_[1] = prel + (l * 4 + 1) * NH; aa.prelB_[1] = prel + (l * 4 + 3) * NH;
        aa.out[0] = (unsigned short*)qb[0]; aa.out[1] = (unsigned short*)qb[1];
        aa.N[0] = Nn[0]; aa.N[1] = Nn[1];
        aa.cum[0] = 0; aa.cum[1] = ganode[0]; aa.cum[2] = ganode[0] + ganode[1];
        agg2<<<aa.cum[2], 256, 0, stream>>>(aa, scale);

        OArgs oa;
        for (int j = 0; j < 2; ++j) {
            oa.A[j] = (const unsigned short*)qb[j];
            oa.W[j] = W2 + offA(l, j);
            oa.bias[j] = ba + (l * 2 + j) * HIDC;
            oa.skipp[j] = skip + (l * 2 + j);
            oa.x[j] = xs[j];
            oa.N[j] = Nn[j];
        }
        oa.cum[0] = 0; oa.cum[1] = gn64[0]; oa.cum[2] = gn64[0] + gn64[1];
        mgemm_op2<<<oa.cum[2], 256, 0, stream>>>(oa);
    }

    cls_kernel<<<(Na + 3) / 4, 256, 0, stream>>>(xs[0], Wcls, bcls, (float*)d_out, Na);
}

// Round 20
// 596.342 us; speedup vs baseline: 1.0046x; 1.0046x over previous
//
#include <hip/hip_runtime.h>
#include <math.h>

#define HIDC 128
#define NH 8
#define HD 16
#define NCLS 4

typedef __attribute__((ext_vector_type(8))) short s8v;
typedef __attribute__((ext_vector_type(4))) float f4v;

#define ST_STRIDE 264   // ushorts per staged split-bf16 row (528 B)
#define ST_BYTES  (64 * ST_STRIDE * 2)   // 33792
#define MNEG (-3.0e38f)  // finite "-inf": state merges never compute inf-inf

__device__ __forceinline__ float gelu_f(float h) {
    float z = 0.7978845608028654f * (h + 0.044715f * h * h * h);
    float t = 1.f - 2.f / (1.f + __expf(2.f * z));   // tanh(z)
    return 0.5f * h * (1.f + t);
}
__device__ __forceinline__ unsigned short f2bf(float x) {
    unsigned b = __float_as_uint(x);
    unsigned r = (b + 0x7FFFu + ((b >> 16) & 1u)) >> 16;
    return (unsigned short)r;
}
__device__ __forceinline__ float bf2f(unsigned short u) {
    return __uint_as_float(((unsigned)u) << 16);
}
__device__ __forceinline__ void gload_lds16(const void* g, void* l) {
    __builtin_amdgcn_global_load_lds(
        (const __attribute__((address_space(1))) unsigned int*)g,
        (__attribute__((address_space(3))) unsigned int*)l, 16, 0, 0);
}

__global__ void zero_u32(unsigned* __restrict__ p, long n)
{
    long i = (long)blockIdx.x * blockDim.x + threadIdx.x;
    long stride = (long)gridDim.x * blockDim.x;
    for (; i < n; i += stride) p[i] = 0u;
}

// Fold relation transforms into K/V projection weights (f32 [k][col]).
__global__ void fold_all(const float* __restrict__ Wk, const float* __restrict__ bk,
                         const float* __restrict__ Wv, const float* __restrict__ bv,
                         const float* __restrict__ arel, const float* __restrict__ mrel,
                         float* __restrict__ Wt, float* __restrict__ bt)
{
    __shared__ float rsh[NH * HD * HD];
    int bid = blockIdx.x;
    int w = bid & 1, r = (bid >> 1) & 3, l = bid >> 3;
    int st = r >> 1;
    const float* W   = (w ? Wv : Wk) + (size_t)(l * 2 + st) * HIDC * HIDC;
    const float* bb  = (w ? bv : bk) + (size_t)(l * 2 + st) * HIDC;
    const float* rel = (w ? mrel : arel) + (size_t)(l * 4 + r) * NH * HD * HD;
    float* wt  = Wt + (size_t)bid * HIDC * HIDC;
    float* btp = bt + (size_t)bid * HIDC;

    int t = threadIdx.x;
    for (int i = t; i < NH * HD * HD; i += 128) rsh[i] = rel[i];
    __syncthreads();
    int h = t >> 4, f = t & 15;
    const float* rh = rsh + h * HD * HD + f;
    for (int k = 0; k < HIDC; ++k) {
        float acc = 0.f;
        const float* wr = W + (size_t)k * HIDC + h * HD;
        #pragma unroll
        for (int d = 0; d < HD; ++d) acc = fmaf(wr[d], rh[d * HD], acc);
        wt[(size_t)k * HIDC + t] = acc;
    }
    float accb = 0.f;
    const float* br = bb + h * HD;
    #pragma unroll
    for (int d = 0; d < HD; ++d) accb = fmaf(br[d], rh[d * HD], accb);
    btp[t] = accb;
}

// Split weights to bf16 hi/lo in MFMA-tiled chunk order.
__global__ __launch_bounds__(128)
void wsplit(const float* __restrict__ linWa, const float* __restrict__ linWb,
            const float* __restrict__ Wq, const float* __restrict__ Wa,
            const float* __restrict__ Wt, unsigned short* __restrict__ W2,
            int Ka, int Kb)
{
    int bid = blockIdx.x;
    int nka = Ka >> 5, nkb = Kb >> 5;
    const float* src; size_t moff; int ks, Km;
    if (bid < nka) { src = linWa; moff = 0; ks = bid; Km = Ka; }
    else if (bid < nka + nkb) { src = linWb; moff = (size_t)2 * Ka * 128; ks = bid - nka; Km = Kb; }
    else {
        int cc = bid - nka - nkb;
        int mm = cc >> 2; ks = cc & 3; Km = 128;
        moff = (size_t)2 * (Ka + Kb) * 128 + (size_t)mm * 32768;
        if (mm < 16)      src = Wt + (size_t)mm * 16384;
        else if (mm < 20) src = Wq + (size_t)(mm - 16) * 16384;
        else              src = Wa + (size_t)(mm - 20) * 16384;
    }
    int t = threadIdx.x;
    int fn = t >> 4, lr = t & 15;
    for (int g = 0; g < 4; ++g)
        for (int j = 0; j < 8; ++j) {
            int k = ks * 32 + g * 8 + j;
            float x = src[(size_t)k * 128 + fn * 16 + lr];
            unsigned short h = f2bf(x);
            size_t co = moff + (size_t)ks * 4096 + fn * 512 + g * 128 + lr * 8 + j;
            W2[co] = h;
            W2[co + (size_t)Km * 128] = f2bf(x - bf2f(h));
        }
}

// ---- CSR build (merged over all 4 edge lists) ----
__global__ void hist4(const int* __restrict__ d0, int E0, const int* __restrict__ d1, int E1,
                      const int* __restrict__ d2, int E2, const int* __restrict__ d3, int E3,
                      unsigned* __restrict__ cnt, int Nmax)
{
    int i = blockIdx.x * blockDim.x + threadIdx.x;
    int tot = E0 + E1 + E2 + E3;
    int stride = gridDim.x * blockDim.x;
    for (; i < tot; i += stride) {
        int j = i; const int* p; int dt;
        if (j < E0) { p = d0; dt = 0; }
        else { j -= E0;
            if (j < E1) { p = d1; dt = 1; }
            else { j -= E1;
                if (j < E2) { p = d2; dt = 0; }
                else { j -= E2; p = d3; dt = 1; }
            }
        }
        atomicAdd(&cnt[(size_t)dt * Nmax + p[j]], 1u);
    }
}

__global__ __launch_bounds__(256)
void scan_p1(const unsigned* __restrict__ cnt, unsigned* __restrict__ bsum,
             int Nmax, int nblk, int n0, int n1)
{
    int ty = blockIdx.x / nblk, b = blockIdx.x % nblk;
    int n = ty ? n1 : n0;
    const unsigned* c = cnt + (size_t)ty * Nmax;
    int i0 = b * 1024 + threadIdx.x * 4;
    unsigned s = 0;
    #pragma unroll
    for (int j = 0; j < 4; ++j) { int i = i0 + j; if (i < n) s += c[i]; }
    __shared__ unsigned sh[256];
    sh[threadIdx.x] = s; __syncthreads();
    for (int off = 128; off; off >>= 1) {
        if (threadIdx.x < (unsigned)off) sh[threadIdx.x] += sh[threadIdx.x + off];
        __syncthreads();
    }
    if (threadIdx.x == 0) bsum[blockIdx.x] = sh[0];
}

__global__ __launch_bounds__(256)
void scan_p2(unsigned* __restrict__ bsum, int nblk, int* __restrict__ rowptr,
             int Nmax, int n0, int n1)
{
    __shared__ unsigned sh[256];
    int tot = 2 * nblk;
    int t = threadIdx.x;
    unsigned v = (t < tot) ? bsum[t] : 0u;
    sh[t] = v; __syncthreads();
    for (int off = 1; off < 256; off <<= 1) {
        unsigned add = (t >= off) ? sh[t - off] : 0u;
        __syncthreads(); sh[t] += add; __syncthreads();
    }
    unsigned t0 = sh[nblk - 1];
    unsigned tall = sh[255];
    unsigned excl = sh[t] - v;
    if (t < tot) bsum[t] = (t < nblk) ? excl : excl - t0;
    if (t == 0) {
        rowptr[n0] = (int)t0;
        rowptr[(Nmax + 1) + n1] = (int)(tall - t0);
    }
}

__global__ __launch_bounds__(256)
void scan_p3(const unsigned* __restrict__ cnt, const unsigned* __restrict__ bsum,
             int* __restrict__ rowptr, unsigned* __restrict__ cursor,
             int Nmax, int nblk, int n0, int n1)
{
    int ty = blockIdx.x / nblk, b = blockIdx.x % nblk;
    int n = ty ? n1 : n0;
    const unsigned* c = cnt + (size_t)ty * Nmax;
    int* rp = rowptr + (size_t)ty * (Nmax + 1);
    unsigned* cur = cursor + (size_t)ty * Nmax;
    int t = threadIdx.x;
    int i0 = b * 1024 + t * 4;
    unsigned v[4]; unsigned s = 0;
    #pragma unroll
    for (int j = 0; j < 4; ++j) { int i = i0 + j; v[j] = (i < n) ? c[i] : 0u; s += v[j]; }
    __shared__ unsigned sh[256];
    sh[t] = s; __syncthreads();
    for (int off = 1; off < 256; off <<= 1) {
        unsigned add = (t >= off) ? sh[t - off] : 0u;
        __syncthreads(); sh[t] += add; __syncthreads();
    }
    unsigned run = bsum[blockIdx.x] + sh[t] - s;
    #pragma unroll
    for (int j = 0; j < 4; ++j) {
        int i = i0 + j;
        if (i < n) { rp[i] = (int)run; cur[i] = run; }
        run += v[j];
    }
}

__global__ void scatter4(const int* __restrict__ e0, int E0, const int* __restrict__ e1, int E1,
                         const int* __restrict__ e2, int E2, const int* __restrict__ e3, int E3,
                         unsigned* __restrict__ cursor, int Nmax,
                         unsigned* __restrict__ adj0, unsigned* __restrict__ adj1)
{
    int i = blockIdx.x * blockDim.x + threadIdx.x;
    int tot = E0 + E1 + E2 + E3;
    int stride = gridDim.x * blockDim.x;
    for (; i < tot; i += stride) {
        int j = i; const int* e; int E; int dt; unsigned rb;
        if (j < E0) { e = e0; E = E0; dt = 0; rb = 0u; }
        else { j -= E0;
            if (j < E1) { e = e1; E = E1; dt = 1; rb = 0u; }
            else { j -= E1;
                if (j < E2) { e = e2; E = E2; dt = 0; rb = 1u << 24; }
                else { j -= E2; e = e3; E = E3; dt = 1; rb = 1u << 24; }
            }
        }
        int s = e[j], d = e[E + j];
        unsigned pos = atomicAdd(&cursor[(size_t)dt * Nmax + d], 1u);
        (dt ? adj1 : adj0)[pos] = (unsigned)s | rb;
    }
}

// ---- single-pass 2-product MFMA GEMM, 64-row tile, 256 thr ----
template <int ASPLIT, int EPI, int OUT, int NK>
__global__ __launch_bounds__(256)
void mg2p(const void* __restrict__ Ain, const unsigned short* __restrict__ Whi,
          const float* __restrict__ bias,
          const unsigned short* __restrict__ xold, const float* __restrict__ skipp,
          void* __restrict__ Cout, int N)
{
    constexpr int K = NK * 32;
    constexpr int PB = NK * 8192;
    constexpr size_t LSZ = (OUT == 2 && ST_BYTES > PB) ? ST_BYTES : PB;
    __shared__ char ldsraw[LSZ];
    unsigned short* lds = (unsigned short*)ldsraw;
    int t = threadIdx.x;
    constexpr int NCP = PB / (16 * 256);
    #pragma unroll
    for (int i = 0; i < NCP; ++i)
        gload_lds16((const char*)Whi + ((size_t)t + i * 256) * 16,
                    ldsraw + ((size_t)t + i * 256) * 16);
    __syncthreads();

    int w = t >> 6, lane = t & 63;
    int lr = lane & 15, g = lane >> 4;
    int row0 = blockIdx.x * 64;
    int fnb = w * 2;

    f4v acc[4][2];
    #pragma unroll
    for (int i = 0; i < 4; ++i) { acc[i][0] = (f4v)0.f; acc[i][1] = (f4v)0.f; }

    #pragma unroll
    for (int ks = 0; ks < NK; ++ks) {
        s8v ah[4], al[4];
        #pragma unroll
        for (int fm = 0; fm < 4; ++fm) {
            int row = row0 + fm * 16 + lr;
            if (row < N) {
                if (ASPLIT) {
                    const unsigned short* ap = (const unsigned short*)Ain + (size_t)row * 256 + ks * 32 + g * 8;
                    ah[fm] = *(const s8v*)ap;
                    al[fm] = *(const s8v*)(ap + 128);
                } else {
                    const float* ap = (const float*)Ain + (size_t)row * K + ks * 32 + g * 8;
                    float4 p = *(const float4*)ap;
                    float4 q = *(const float4*)(ap + 4);
                    float xv[8] = {p.x, p.y, p.z, p.w, q.x, q.y, q.z, q.w};
                    #pragma unroll
                    for (int j = 0; j < 8; ++j) {
                        unsigned short h = f2bf(xv[j]);
                        ah[fm][j] = (short)h;
                        al[fm][j] = (short)f2bf(xv[j] - bf2f(h));
                    }
                }
            } else { ah[fm] = (s8v)0; al[fm] = (s8v)0; }
        }
        #pragma unroll
        for (int f = 0; f < 2; ++f) {
            size_t co = (size_t)ks * 8192 + (fnb + f) * 1024 + g * 256 + lr * 16;
            s8v b = *(const s8v*)(ldsraw + co);
            #pragma unroll
            for (int fm = 0; fm < 4; ++fm) {
                acc[fm][f] = __builtin_amdgcn_mfma_f32_16x16x32_bf16(ah[fm], b, acc[fm][f], 0, 0, 0);
                acc[fm][f] = __builtin_amdgcn_mfma_f32_16x16x32_bf16(al[fm], b, acc[fm][f], 0, 0, 0);
            }
        }
    }

    float beta = 0.f;
    if (EPI == 2) beta = 1.f / (1.f + __expf(-skipp[0]));
    int rb = g * 4;

    if (OUT == 2) {
        __syncthreads();
        #pragma unroll
        for (int f = 0; f < 2; ++f) {
            int col = (fnb + f) * 16 + lr;
            float bv = bias[col];
            #pragma unroll
            for (int fm = 0; fm < 4; ++fm) {
                #pragma unroll
                for (int j = 0; j < 4; ++j) {
                    int lrow = fm * 16 + rb + j;
                    int row = row0 + lrow;
                    float o = acc[fm][f][j] + bv;
                    if (EPI == 1) o = fmaxf(o, 0.f);
                    if (EPI == 2) {
                        float xo = (row < N) ? (bf2f(xold[(size_t)row * 256 + col]) +
                                                bf2f(xold[(size_t)row * 256 + 128 + col])) : 0.f;
                        o = beta * o + (1.f - beta) * xo;
                    }
                    unsigned short h = f2bf(o);
                    lds[(size_t)lrow * ST_STRIDE + col] = h;
                    lds[(size_t)lrow * ST_STRIDE + 128 + col] = f2bf(o - bf2f(h));
                }
            }
        }
        __syncthreads();
        unsigned short* C = (unsigned short*)Cout;
        #pragma unroll
        for (int it = 0; it < 8; ++it) {
            int d4 = (it * 256 + t) * 4;
            int row = d4 >> 7, c2 = d4 & 127;
            int grow = row0 + row;
            if (grow < N) {
                uint4 v = *(const uint4*)(lds + (size_t)row * ST_STRIDE + c2 * 2);
                *(uint4*)(C + (size_t)grow * 256 + c2 * 2) = v;
            }
        }
    } else {
        float* C = (float*)Cout;
        #pragma unroll
        for (int f = 0; f < 2; ++f) {
            int col = (fnb + f) * 16 + lr;
            float bv = bias[col];
            #pragma unroll
            for (int fm = 0; fm < 4; ++fm) {
                #pragma unroll
                for (int j = 0; j < 4; ++j) {
                    int row = row0 + fm * 16 + rb + j;
                    if (row < N) C[(size_t)row * HIDC + col] = acc[fm][f][j] + bv;
                }
            }
        }
    }
}

// ---- batched dual kv GEMM: 4 jobs (st,dt), 64-row tile, 2-product ----
struct KvArgs {
    const unsigned short* A[4];
    const unsigned short* Wm[4];
    const float* bias[4];
    unsigned short* out[4];
    int N[4];
    int cum[5];
};

__global__ __launch_bounds__(256)
void mgemm_kv4(KvArgs args)
{
    int bid = blockIdx.x;
    int jb = 0;
    while (jb < 3 && bid >= args.cum[jb + 1]) ++jb;
    int lb = bid - args.cum[jb];
    const unsigned short* Ain = args.A[jb];
    const unsigned short* Wkt = args.Wm[jb];
    const unsigned short* Wvt = args.Wm[jb] + 32768;
    const float* bias2 = args.bias[jb];
    unsigned short* kv = args.out[jb];
    int N = args.N[jb];

    __shared__ char ldsraw[65536];
    unsigned short* lds = (unsigned short*)ldsraw;
    int t = threadIdx.x;
    #pragma unroll
    for (int i = 0; i < 8; ++i)
        gload_lds16((const char*)Wkt + ((size_t)t + i * 256) * 16,
                    ldsraw + ((size_t)t + i * 256) * 16);
    #pragma unroll
    for (int i = 0; i < 8; ++i)
        gload_lds16((const char*)Wvt + ((size_t)t + i * 256) * 16,
                    ldsraw + 32768 + ((size_t)t + i * 256) * 16);

    int w = t >> 6, lane = t & 63;
    int lr = lane & 15, g = lane >> 4;
    int row0 = lb * 64;
    int fnb = w * 2;

    s8v ah[4][4], al[4][4];
    #pragma unroll
    for (int fm = 0; fm < 4; ++fm) {
        int row = row0 + fm * 16 + lr;
        #pragma unroll
        for (int ks = 0; ks < 4; ++ks) {
            if (row < N) {
                const unsigned short* ap = Ain + (size_t)row * 256 + ks * 32 + g * 8;
                ah[fm][ks] = *(const s8v*)ap;
                al[fm][ks] = *(const s8v*)(ap + 128);
            } else { ah[fm][ks] = (s8v)0; al[fm][ks] = (s8v)0; }
        }
    }
    __syncthreads();

    f4v acck[4][2], accv[4][2];
    #pragma unroll
    for (int i = 0; i < 4; ++i) {
        acck[i][0] = (f4v)0.f; acck[i][1] = (f4v)0.f;
        accv[i][0] = (f4v)0.f; accv[i][1] = (f4v)0.f;
    }

    #pragma unroll
    for (int ks = 0; ks < 4; ++ks) {
        #pragma unroll
        for (int f = 0; f < 2; ++f) {
            int fn = fnb + f;
            size_t co = (size_t)ks * 8192 + fn * 1024 + g * 256 + lr * 16;
            s8v bk_ = *(const s8v*)(ldsraw + co);
            s8v bv_ = *(const s8v*)(ldsraw + 32768 + co);
            #pragma unroll
            for (int fm = 0; fm < 4; ++fm) {
                acck[fm][f] = __builtin_amdgcn_mfma_f32_16x16x32_bf16(ah[fm][ks], bk_, acck[fm][f], 0, 0, 0);
                acck[fm][f] = __builtin_amdgcn_mfma_f32_16x16x32_bf16(al[fm][ks], bk_, acck[fm][f], 0, 0, 0);
                accv[fm][f] = __builtin_amdgcn_mfma_f32_16x16x32_bf16(ah[fm][ks], bv_, accv[fm][f], 0, 0, 0);
                accv[fm][f] = __builtin_amdgcn_mfma_f32_16x16x32_bf16(al[fm][ks], bv_, accv[fm][f], 0, 0, 0);
            }
        }
    }

    __syncthreads();
    int rb = g * 4;
    #pragma unroll
    for (int f = 0; f < 2; ++f) {
        int fn = fnb + f;
        int col = fn * 16 + lr;
        float bk0 = bias2[col], bv0 = bias2[128 + col];
        #pragma unroll
        for (int fm = 0; fm < 4; ++fm) {
            #pragma unroll
            for (int j = 0; j < 4; ++j) {
                int lrow = fm * 16 + rb + j;
                lds[(size_t)lrow * ST_STRIDE + col] = f2bf(acck[fm][f][j] + bk0);
                lds[(size_t)lrow * ST_STRIDE + 128 + col] = f2bf(accv[fm][f][j] + bv0);
            }
        }
    }
    __syncthreads();
    #pragma unroll
    for (int it = 0; it < 8; ++it) {
        int d4 = (it * 256 + t) * 4;
        int row = d4 >> 7, c2 = d4 & 127;
        int grow = row0 + row;
        if (grow < N) {
            uint4 v = *(const uint4*)(lds + (size_t)row * ST_STRIDE + c2 * 2);
            *(uint4*)(kv + (size_t)grow * 256 + c2 * 2) = v;
        }
    }
}

// ---- batched q GEMM: 2 jobs, 64-row tile, 2-product, f32 out ----
struct QArgs {
    const unsigned short* A[2];
    const unsigned short* W[2];
    const float* bias[2];
    float* out[2];
    int N[2];
    int cum[3];
};

__global__ __launch_bounds__(256)
void mgemm_q2(QArgs args)
{
    int bid = blockIdx.x;
    int jb = (bid >= args.cum[1]) ? 1 : 0;
    int lb = bid - args.cum[jb];
    const unsigned short* Ain = args.A[jb];
    const unsigned short* Whi = args.W[jb];
    const float* bias = args.bias[jb];
    float* Cout = args.out[jb];
    int N = args.N[jb];

    __shared__ char ldsraw[32768];
    int t = threadIdx.x;
    #pragma unroll
    for (int i = 0; i < 8; ++i)
        gload_lds16((const char*)Whi + ((size_t)t + i * 256) * 16,
                    ldsraw + ((size_t)t + i * 256) * 16);
    __syncthreads();

    int w = t >> 6, lane = t & 63;
    int lr = lane & 15, g = lane >> 4;
    int row0 = lb * 64;
    int fnb = w * 2;

    f4v acc[4][2];
    #pragma unroll
    for (int i = 0; i < 4; ++i) { acc[i][0] = (f4v)0.f; acc[i][1] = (f4v)0.f; }

    #pragma unroll
    for (int ks = 0; ks < 4; ++ks) {
        s8v ah[4], al[4];
        #pragma unroll
        for (int fm = 0; fm < 4; ++fm) {
            int row = row0 + fm * 16 + lr;
            if (row < N) {
                const unsigned short* ap = Ain + (size_t)row * 256 + ks * 32 + g * 8;
                ah[fm] = *(const s8v*)ap;
                al[fm] = *(const s8v*)(ap + 128);
            } else { ah[fm] = (s8v)0; al[fm] = (s8v)0; }
        }
        #pragma unroll
        for (int f = 0; f < 2; ++f) {
            size_t co = (size_t)ks * 8192 + (fnb + f) * 1024 + g * 256 + lr * 16;
            s8v b = *(const s8v*)(ldsraw + co);
            #pragma unroll
            for (int fm = 0; fm < 4; ++fm) {
                acc[fm][f] = __builtin_amdgcn_mfma_f32_16x16x32_bf16(ah[fm], b, acc[fm][f], 0, 0, 0);
                acc[fm][f] = __builtin_amdgcn_mfma_f32_16x16x32_bf16(al[fm], b, acc[fm][f], 0, 0, 0);
            }
        }
    }

    int rb = g * 4;
    #pragma unroll
    for (int f = 0; f < 2; ++f) {
        int col = (fnb + f) * 16 + lr;
        float bv = bias[col];
        #pragma unroll
        for (int fm = 0; fm < 4; ++fm) {
            #pragma unroll
            for (int j = 0; j < 4; ++j) {
                int row = row0 + fm * 16 + rb + j;
                if (row < N) Cout[(size_t)row * HIDC + col] = acc[fm][f][j] + bv;
            }
        }
    }
}

// ---- batched outproj GEMM: 2 jobs, 64-row tile, 2-product, skip-blend, in-place ----
struct OArgs {
    const unsigned short* A[2];
    const unsigned short* W[2];
    const float* bias[2];
    const float* skipp[2];
    unsigned short* x[2];
    int N[2];
    int cum[3];
};

__global__ __launch_bounds__(256)
void mgemm_op2(OArgs args)
{
    int bid = blockIdx.x;
    int jb = (bid >= args.cum[1]) ? 1 : 0;
    int lb = bid - args.cum[jb];
    const unsigned short* Ain = args.A[jb];
    const unsigned short* Whi = args.W[jb];
    const float* bias = args.bias[jb];
    const unsigned short* xold = args.x[jb];
    unsigned short* Cout = args.x[jb];
    float beta = 1.f / (1.f + __expf(-args.skipp[jb][0]));
    int N = args.N[jb];

    __shared__ char ldsraw[ST_BYTES];
    unsigned short* lds = (unsigned short*)ldsraw;
    int t = threadIdx.x;
    #pragma unroll
    for (int i = 0; i < 8; ++i)
        gload_lds16((const char*)Whi + ((size_t)t + i * 256) * 16,
                    ldsraw + ((size_t)t + i * 256) * 16);
    __syncthreads();

    int w = t >> 6, lane = t & 63;
    int lr = lane & 15, g = lane >> 4;
    int row0 = lb * 64;
    int fnb = w * 2;

    f4v acc[4][2];
    #pragma unroll
    for (int i = 0; i < 4; ++i) { acc[i][0] = (f4v)0.f; acc[i][1] = (f4v)0.f; }

    #pragma unroll
    for (int ks = 0; ks < 4; ++ks) {
        s8v ah[4], al[4];
        #pragma unroll
        for (int fm = 0; fm < 4; ++fm) {
            int row = row0 + fm * 16 + lr;
            if (row < N) {
                const unsigned short* ap = Ain + (size_t)row * 256 + ks * 32 + g * 8;
                ah[fm] = *(const s8v*)ap;
                al[fm] = *(const s8v*)(ap + 128);
            } else { ah[fm] = (s8v)0; al[fm] = (s8v)0; }
        }
        #pragma unroll
        for (int f = 0; f < 2; ++f) {
            size_t co = (size_t)ks * 8192 + (fnb + f) * 1024 + g * 256 + lr * 16;
            s8v b = *(const s8v*)(ldsraw + co);
            #pragma unroll
            for (int fm = 0; fm < 4; ++fm) {
                acc[fm][f] = __builtin_amdgcn_mfma_f32_16x16x32_bf16(ah[fm], b, acc[fm][f], 0, 0, 0);
                acc[fm][f] = __builtin_amdgcn_mfma_f32_16x16x32_bf16(al[fm], b, acc[fm][f], 0, 0, 0);
            }
        }
    }

    int rb = g * 4;
    __syncthreads();
    #pragma unroll
    for (int f = 0; f < 2; ++f) {
        int col = (fnb + f) * 16 + lr;
        float bv = bias[col];
        #pragma unroll
        for (int fm = 0; fm < 4; ++fm) {
            #pragma unroll
            for (int j = 0; j < 4; ++j) {
                int lrow = fm * 16 + rb + j;
                int row = row0 + lrow;
                float o = acc[fm][f][j] + bv;
                float xo = (row < N) ? (bf2f(xold[(size_t)row * 256 + col]) +
                                        bf2f(xold[(size_t)row * 256 + 128 + col])) : 0.f;
                o = beta * o + (1.f - beta) * xo;
                unsigned short h = f2bf(o);
                lds[(size_t)lrow * ST_STRIDE + col] = h;
                lds[(size_t)lrow * ST_STRIDE + 128 + col] = f2bf(o - bf2f(h));
            }
        }
    }
    __syncthreads();
    #pragma unroll
    for (int it = 0; it < 8; ++it) {
        int d4 = (it * 256 + t) * 4;
        int row = d4 >> 7, c2 = d4 & 127;
        int grow = row0 + row;
        if (grow < N) {
            uint4 v = *(const uint4*)(lds + (size_t)row * ST_STRIDE + c2 * 2);
            *(uint4*)(Cout + (size_t)grow * 256 + c2 * 2) = v;
        }
    }
}

// ---- batched fused aggregation: 2 jobs (dt 0/1); wave/node, single-exp online SM ----
#define EDGE_STEP(IDX, M, S, AX, AY)                                               \
    {                                                                              \
        unsigned ent = adj[IDX];                                                   \
        int src = (int)(ent & 0xFFFFFFu);                                          \
        const unsigned short* kv = (ent >> 24) ? kvB : kvA;                        \
        float sp = (ent >> 24) ? spB : spA;                                        \
        ushort2 kraw = *(const ushort2*)(kv + (size_t)src * 256 + lane * 2);       \
        ushort2 vraw = *(const ushort2*)(kv + (size_t)src * 256 + 128 + lane * 2); \
        float p = bf2f(kraw.x) * qv.x + bf2f(kraw.y) * qv.y;                       \
        p += __shfl_xor(p, 1, 8);                                                  \
        p += __shfl_xor(p, 2, 8);                                                  \
        p += __shfl_xor(p, 4, 8);                                                  \
        float a = p * sp;                                                          \
        float d = a - M;                                                           \
        float e = __expf(-fabsf(d));                                               \
        bool nm = d > 0.f;                                                         \
        float sc = nm ? e : 1.f;                                                   \
        float pw = nm ? 1.f : e;                                                   \
        S = S * sc + pw;                                                           \
        AX = AX * sc + pw * bf2f(vraw.x);                                          \
        AY = AY * sc + pw * bf2f(vraw.y);                                          \
        M = nm ? a : M;                                                            \
    }

struct AArgs {
    const float* Q[2];
    const unsigned short* kvA_[2];
    const unsigned short* kvB_[2];
    const int* rowptr[2];
    const unsigned* adjp[2];
    const float* prelA_[2];
    const float* prelB_[2];
    unsigned short* out[2];   // aliases Q (same buffer reinterpreted)
    int N[2];
    int cum[3];
};

__global__ __launch_bounds__(256)
void agg2(AArgs args, float scale)
{
    int bid = blockIdx.x;
    int jb = (bid >= args.cum[1]) ? 1 : 0;
    int lb = bid - args.cum[jb];
    const float* Q = args.Q[jb];
    const unsigned short* kvA = args.kvA_[jb];
    const unsigned short* kvB = args.kvB_[jb];
    const int* rowptr = args.rowptr[jb];
    const unsigned* adj = args.adjp[jb];
    unsigned short* msgs = args.out[jb];
    int N = args.N[jb];

    int node = lb * 4 + (threadIdx.x >> 6);
    if (node >= N) return;
    int lane = threadIdx.x & 63;
    int h = lane >> 3;
    float spA = args.prelA_[jb][h] * scale, spB = args.prelB_[jb][h] * scale;
    float2 qv = *(const float2*)(Q + (size_t)node * HIDC + lane * 2);
    int beg = rowptr[node], end = rowptr[node + 1];

    float m0 = MNEG, s0 = 0.f, ax0 = 0.f, ay0 = 0.f;
    float m1 = MNEG, s1 = 0.f, ax1 = 0.f, ay1 = 0.f;
    int i = beg;
    for (; i + 1 < end; i += 2) {
        EDGE_STEP(i,     m0, s0, ax0, ay0);
        EDGE_STEP(i + 1, m1, s1, ax1, ay1);
    }
    if (i < end) EDGE_STEP(i, m0, s0, ax0, ay0);

    float ox = 0.f, oy = 0.f;
    if (end > beg) {
        float mn = fmaxf(m0, m1);
        float c0 = __expf(m0 - mn), c1 = __expf(m1 - mn);
        float s = s0 * c0 + s1 * c1;
        float inv = 1.f / fmaxf(s, 1e-16f);
        ox = (ax0 * c0 + ax1 * c1) * inv;
        oy = (ay0 * c0 + ay1 * c1) * inv;
    }
    ox = gelu_f(ox); oy = gelu_f(oy);
    unsigned short hx = f2bf(ox), hy = f2bf(oy);
    size_t base = (size_t)node * 256 + lane * 2;
    ushort2 hi2; hi2.x = hx; hi2.y = hy;
    ushort2 lo2; lo2.x = f2bf(ox - bf2f(hx)); lo2.y = f2bf(oy - bf2f(hy));
    *(ushort2*)(msgs + base) = hi2;
    *(ushort2*)(msgs + base + 128) = lo2;
}

// ---- classifier: one wave per row, x split-bf16 ----
__global__ __launch_bounds__(256)
void cls_kernel(const unsigned short* __restrict__ X, const float* __restrict__ Wc,
                const float* __restrict__ bc, float* __restrict__ out, int N)
{
    int row = blockIdx.x * 4 + (threadIdx.x >> 6);
    if (row >= N) return;
    int lane = threadIdx.x & 63;
    const unsigned short* xr = X + (size_t)row * 256 + lane * 2;
    float x0 = bf2f(xr[0]) + bf2f(xr[128]);
    float x1 = bf2f(xr[1]) + bf2f(xr[129]);
    float p0, p1, p2, p3;
    {
        float2 w0 = *(const float2*)(Wc + 0 * HIDC + lane * 2);
        float2 w1 = *(const float2*)(Wc + 1 * HIDC + lane * 2);
        float2 w2 = *(const float2*)(Wc + 2 * HIDC + lane * 2);
        float2 w3 = *(const float2*)(Wc + 3 * HIDC + lane * 2);
        p0 = x0 * w0.x + x1 * w0.y;
        p1 = x0 * w1.x + x1 * w1.y;
        p2 = x0 * w2.x + x1 * w2.y;
        p3 = x0 * w3.x + x1 * w3.y;
    }
    #pragma unroll
    for (int off = 32; off; off >>= 1) {
        p0 += __shfl_xor(p0, off);
        p1 += __shfl_xor(p1, off);
        p2 += __shfl_xor(p2, off);
        p3 += __shfl_xor(p3, off);
    }
    if (lane < 4) {
        float v = (lane == 0) ? p0 : (lane == 1) ? p1 : (lane == 2) ? p2 : p3;
        out[(size_t)row * NCLS + lane] = v + bc[lane];
    }
}

extern "C" void kernel_launch(void* const* d_in, const int* in_sizes, int n_in,
                              void* d_out, int out_size, void* d_ws, size_t ws_size,
                              hipStream_t stream)
{
    const float* x_a    = (const float*)d_in[0];
    const float* x_b    = (const float*)d_in[1];
    const float* lin_W_a= (const float*)d_in[2];
    const float* lin_b_a= (const float*)d_in[3];
    const float* lin_W_b= (const float*)d_in[4];
    const float* lin_b_b= (const float*)d_in[5];
    const float* Wk     = (const float*)d_in[6];
    const float* bk     = (const float*)d_in[7];
    const float* Wq     = (const float*)d_in[8];
    const float* bq     = (const float*)d_in[9];
    const float* Wv     = (const float*)d_in[10];
    const float* bv     = (const float*)d_in[11];
    const float* arel   = (const float*)d_in[12];
    const float* mrel   = (const float*)d_in[13];
    const float* prel   = (const float*)d_in[14];
    const float* Wa     = (const float*)d_in[15];
    const float* ba     = (const float*)d_in[16];
    const float* skip   = (const float*)d_in[17];
    const float* Wcls   = (const float*)d_in[18];
    const float* bcls   = (const float*)d_in[19];
    const int* eptr[4] = {(const int*)d_in[20], (const int*)d_in[21],
                          (const int*)d_in[22], (const int*)d_in[23]};
    int Ee[4] = {in_sizes[20] / 2, in_sizes[21] / 2, in_sizes[22] / 2, in_sizes[23] / 2};

    int Ka = in_sizes[2] / HIDC;     // 64
    int Kb = in_sizes[4] / HIDC;     // 32
    int Na = in_sizes[0] / Ka;
    int Nb = in_sizes[1] / Kb;
    int Nn[2] = {Na, Nb};
    int Nmax = Na > Nb ? Na : Nb;

    // ---- workspace layout (~212 MB) ----
    char* base = (char*)d_ws;
    unsigned short* xs[2];
    xs[0] = (unsigned short*)base; base += (size_t)Na * 256 * 2;
    xs[1] = (unsigned short*)base; base += (size_t)Nb * 256 * 2;
    float* qb[2];            // q f32; after agg, reused as split-bf16 msgs
    qb[0] = (float*)base; base += (size_t)Na * HIDC * 4;
    qb[1] = (float*)base; base += (size_t)Nb * HIDC * 4;
    unsigned short* kvb[2][2];
    for (int s = 0; s < 2; ++s)
        for (int d = 0; d < 2; ++d) { kvb[s][d] = (unsigned short*)base; base += (size_t)Nn[s] * 256 * 2; }
    float* Wt = (float*)base; base += (size_t)16 * HIDC * HIDC * 4;
    float* bt = (float*)base; base += (size_t)16 * HIDC * 4;
    size_t nW2 = (size_t)2 * (Ka + Kb) * 128 + (size_t)24 * 32768;  // ushorts
    unsigned short* W2 = (unsigned short*)base; base += nW2 * 2;
    unsigned* cnt = (unsigned*)base; base += (size_t)2 * Nmax * 4;
    unsigned* cursor = (unsigned*)base; base += (size_t)2 * Nmax * 4;
    unsigned* bsum = (unsigned*)base; base += 256 * 4;
    int* rowptr = (int*)base; base += (size_t)2 * (Nmax + 1) * 4;
    unsigned* adj0 = (unsigned*)base; base += (size_t)(Ee[0] + Ee[2]) * 4;
    unsigned* adj1 = (unsigned*)base; base += (size_t)(Ee[1] + Ee[3]) * 4;

    // W2 mat offsets (ushorts)
    size_t off_lina = 0;
    size_t off_linb = (size_t)2 * Ka * 128;
    size_t base128  = (size_t)2 * (Ka + Kb) * 128;
    auto offKT = [&](int l, int st, int dt) { return base128 + (size_t)(l * 8 + (st * 2 + dt) * 2) * 32768; };
    auto offQ  = [&](int l, int tt) { return base128 + (size_t)(16 + l * 2 + tt) * 32768; };
    auto offA  = [&](int l, int tt) { return base128 + (size_t)(20 + l * 2 + tt) * 32768; };

    // ---- weight prep ----
    fold_all<<<16, 128, 0, stream>>>(Wk, bk, Wv, bv, arel, mrel, Wt, bt);
    int nwblk = (Ka >> 5) + (Kb >> 5) + 24 * 4;
    wsplit<<<nwblk, 128, 0, stream>>>(lin_W_a, lin_W_b, Wq, Wa, Wt, W2, Ka, Kb);

    // ---- CSR build ----
    int nblk = (Nmax + 1023) / 1024;
    zero_u32<<<512, 256, 0, stream>>>(cnt, (long)2 * Nmax);
    hist4<<<1024, 256, 0, stream>>>(eptr[0] + Ee[0], Ee[0], eptr[1] + Ee[1], Ee[1],
                                    eptr[2] + Ee[2], Ee[2], eptr[3] + Ee[3], Ee[3],
                                    cnt, Nmax);
    scan_p1<<<2 * nblk, 256, 0, stream>>>(cnt, bsum, Nmax, nblk, Na, Nb);
    scan_p2<<<1, 256, 0, stream>>>(bsum, nblk, rowptr, Nmax, Na, Nb);
    scan_p3<<<2 * nblk, 256, 0, stream>>>(cnt, bsum, rowptr, cursor, Nmax, nblk, Na, Nb);
    scatter4<<<1024, 256, 0, stream>>>(eptr[0], Ee[0], eptr[1], Ee[1],
                                       eptr[2], Ee[2], eptr[3], Ee[3],
                                       cursor, Nmax, adj0, adj1);

    // ---- input projections + ReLU -> split-bf16 x ----
    int gn64[2] = {(Na + 63) / 64, (Nb + 63) / 64};
    mg2p<0, 1, 2, 2><<<gn64[0], 256, 0, stream>>>(x_a, W2 + off_lina, lin_b_a,
                                                  nullptr, nullptr, xs[0], Na);
    mg2p<0, 1, 2, 1><<<gn64[1], 256, 0, stream>>>(x_b, W2 + off_linb, lin_b_b,
                                                  nullptr, nullptr, xs[1], Nb);

    const float scale = 0.25f;   // 1/sqrt(16)
    int ganode[2] = {(Na + 3) / 4, (Nb + 3) / 4};

    for (int l = 0; l < 2; ++l) {
        KvArgs ka;
        int cum = 0;
        for (int j = 0; j < 4; ++j) {
            int st = j >> 1, dt = j & 1;
            int bid = l * 8 + (st * 2 + dt) * 2;
            ka.A[j] = xs[st];
            ka.Wm[j] = W2 + offKT(l, st, dt);
            ka.bias[j] = bt + (size_t)bid * HIDC;
            ka.out[j] = kvb[st][dt];
            ka.N[j] = Nn[st];
            ka.cum[j] = cum;
            cum += gn64[st];
        }
        ka.cum[4] = cum;
        mgemm_kv4<<<cum, 256, 0, stream>>>(ka);

        QArgs qa;
        for (int j = 0; j < 2; ++j) {
            qa.A[j] = xs[j];
            qa.W[j] = W2 + offQ(l, j);
            qa.bias[j] = bq + (l * 2 + j) * HIDC;
            qa.out[j] = qb[j];
            qa.N[j] = Nn[j];
        }
        qa.cum[0] = 0; qa.cum[1] = gn64[0]; qa.cum[2] = gn64[0] + gn64[1];
        mgemm_q2<<<qa.cum[2], 256, 0, stream>>>(qa);

        AArgs aa;
        aa.Q[0] = qb[0]; aa.Q[1] = qb[1];
        aa.kvA_[0] = kvb[0][0]; aa.kvB_[0] = kvb[1][0];
        aa.kvA_[1] = kvb[0][1]; aa.kvB_[1] = kvb[1][1];
        aa.rowptr[0] = rowptr; aa.rowptr[1] = rowptr + (Nmax + 1);
        aa.adjp[0] = adj0; aa.adjp[1] = adj1;
        aa.prelA_[0] = prel + (l * 4 + 0) * NH; aa.prelB_[0] = prel + (l * 4 + 2) * NH;
        aa.prelA_[1] = prel + (l * 4 + 1) * NH; aa.prelB_[1] = prel + (l * 4 + 3) * NH;
        aa.out[0] = (unsigned short*)qb[0]; aa.out[1] = (unsigned short*)qb[1];
        aa.N[0] = Nn[0]; aa.N[1] = Nn[1];
        aa.cum[0] = 0; aa.cum[1] = ganode[0]; aa.cum[2] = ganode[0] + ganode[1];
        agg2<<<aa.cum[2], 256, 0, stream>>>(aa, scale);

        OArgs oa;
        for (int j = 0; j < 2; ++j) {
            oa.A[j] = (const unsigned short*)qb[j];
            oa.W[j] = W2 + offA(l, j);
            oa.bias[j] = ba + (l * 2 + j) * HIDC;
            oa.skipp[j] = skip + (l * 2 + j);
            oa.x[j] = xs[j];
            oa.N[j] = Nn[j];
        }
        oa.cum[0] = 0; oa.cum[1] = gn64[0]; oa.cum[2] = gn64[0] + gn64[1];
        mgemm_op2<<<oa.cum[2], 256, 0, stream>>>(oa);
    }

    cls_kernel<<<(Na + 3) / 4, 256, 0, stream>>>(xs[0], Wcls, bcls, (float*)d_out, Na);
}

// Round 21
// 569.117 us; speedup vs baseline: 1.0527x; 1.0478x over previous
//
#include <hip/hip_runtime.h>
#include <math.h>

#define HIDC 128
#define NH 8
#define HD 16
#define NCLS 4

typedef __attribute__((ext_vector_type(8))) short s8v;
typedef __attribute__((ext_vector_type(4))) float f4v;

#define ST_STRIDE 264   // ushorts per staged row (528 B, proven 0-conflict)
#define ST_BYTES  (64 * ST_STRIDE * 2)   // 33792
#define MNEG (-3.0e38f)  // finite "-inf": state merges never compute inf-inf

__device__ __forceinline__ float gelu_f(float h) {
    float z = 0.7978845608028654f * (h + 0.044715f * h * h * h);
    float t = 1.f - 2.f / (1.f + __expf(2.f * z));   // tanh(z)
    return 0.5f * h * (1.f + t);
}
__device__ __forceinline__ unsigned short f2bf(float x) {
    unsigned b = __float_as_uint(x);
    unsigned r = (b + 0x7FFFu + ((b >> 16) & 1u)) >> 16;
    return (unsigned short)r;
}
__device__ __forceinline__ float bf2f(unsigned short u) {
    return __uint_as_float(((unsigned)u) << 16);
}
__device__ __forceinline__ void gload_lds16(const void* g, void* l) {
    __builtin_amdgcn_global_load_lds(
        (const __attribute__((address_space(1))) unsigned int*)g,
        (__attribute__((address_space(3))) unsigned int*)l, 16, 0, 0);
}

__global__ void zero_u32(unsigned* __restrict__ p, long n)
{
    long i = (long)blockIdx.x * blockDim.x + threadIdx.x;
    long stride = (long)gridDim.x * blockDim.x;
    for (; i < n; i += stride) p[i] = 0u;
}

// Fold relation transforms into K/V projection weights (f32 [k][col]).
__global__ void fold_all(const float* __restrict__ Wk, const float* __restrict__ bk,
                         const float* __restrict__ Wv, const float* __restrict__ bv,
                         const float* __restrict__ arel, const float* __restrict__ mrel,
                         float* __restrict__ Wt, float* __restrict__ bt)
{
    __shared__ float rsh[NH * HD * HD];
    int bid = blockIdx.x;
    int w = bid & 1, r = (bid >> 1) & 3, l = bid >> 3;
    int st = r >> 1;
    const float* W   = (w ? Wv : Wk) + (size_t)(l * 2 + st) * HIDC * HIDC;
    const float* bb  = (w ? bv : bk) + (size_t)(l * 2 + st) * HIDC;
    const float* rel = (w ? mrel : arel) + (size_t)(l * 4 + r) * NH * HD * HD;
    float* wt  = Wt + (size_t)bid * HIDC * HIDC;
    float* btp = bt + (size_t)bid * HIDC;

    int t = threadIdx.x;
    for (int i = t; i < NH * HD * HD; i += 128) rsh[i] = rel[i];
    __syncthreads();
    int h = t >> 4, f = t & 15;
    const float* rh = rsh + h * HD * HD + f;
    for (int k = 0; k < HIDC; ++k) {
        float acc = 0.f;
        const float* wr = W + (size_t)k * HIDC + h * HD;
        #pragma unroll
        for (int d = 0; d < HD; ++d) acc = fmaf(wr[d], rh[d * HD], acc);
        wt[(size_t)k * HIDC + t] = acc;
    }
    float accb = 0.f;
    const float* br = bb + h * HD;
    #pragma unroll
    for (int d = 0; d < HD; ++d) accb = fmaf(br[d], rh[d * HD], accb);
    btp[t] = accb;
}

// Split weights to bf16 hi/lo in MFMA-tiled chunk order.
__global__ __launch_bounds__(128)
void wsplit(const float* __restrict__ linWa, const float* __restrict__ linWb,
            const float* __restrict__ Wq, const float* __restrict__ Wa,
            const float* __restrict__ Wt, unsigned short* __restrict__ W2,
            int Ka, int Kb)
{
    int bid = blockIdx.x;
    int nka = Ka >> 5, nkb = Kb >> 5;
    const float* src; size_t moff; int ks, Km;
    if (bid < nka) { src = linWa; moff = 0; ks = bid; Km = Ka; }
    else if (bid < nka + nkb) { src = linWb; moff = (size_t)2 * Ka * 128; ks = bid - nka; Km = Kb; }
    else {
        int cc = bid - nka - nkb;
        int mm = cc >> 2; ks = cc & 3; Km = 128;
        moff = (size_t)2 * (Ka + Kb) * 128 + (size_t)mm * 32768;
        if (mm < 16)      src = Wt + (size_t)mm * 16384;
        else if (mm < 20) src = Wq + (size_t)(mm - 16) * 16384;
        else              src = Wa + (size_t)(mm - 20) * 16384;
    }
    int t = threadIdx.x;
    int fn = t >> 4, lr = t & 15;
    for (int g = 0; g < 4; ++g)
        for (int j = 0; j < 8; ++j) {
            int k = ks * 32 + g * 8 + j;
            float x = src[(size_t)k * 128 + fn * 16 + lr];
            unsigned short h = f2bf(x);
            size_t co = moff + (size_t)ks * 4096 + fn * 512 + g * 128 + lr * 8 + j;
            W2[co] = h;
            W2[co + (size_t)Km * 128] = f2bf(x - bf2f(h));
        }
}

// ---- CSR build (merged over all 4 edge lists) ----
__global__ void hist4(const int* __restrict__ d0, int E0, const int* __restrict__ d1, int E1,
                      const int* __restrict__ d2, int E2, const int* __restrict__ d3, int E3,
                      unsigned* __restrict__ cnt, int Nmax)
{
    int i = blockIdx.x * blockDim.x + threadIdx.x;
    int tot = E0 + E1 + E2 + E3;
    int stride = gridDim.x * blockDim.x;
    for (; i < tot; i += stride) {
        int j = i; const int* p; int dt;
        if (j < E0) { p = d0; dt = 0; }
        else { j -= E0;
            if (j < E1) { p = d1; dt = 1; }
            else { j -= E1;
                if (j < E2) { p = d2; dt = 0; }
                else { j -= E2; p = d3; dt = 1; }
            }
        }
        atomicAdd(&cnt[(size_t)dt * Nmax + p[j]], 1u);
    }
}

__global__ __launch_bounds__(256)
void scan_p1(const unsigned* __restrict__ cnt, unsigned* __restrict__ bsum,
             int Nmax, int nblk, int n0, int n1)
{
    int ty = blockIdx.x / nblk, b = blockIdx.x % nblk;
    int n = ty ? n1 : n0;
    const unsigned* c = cnt + (size_t)ty * Nmax;
    int i0 = b * 1024 + threadIdx.x * 4;
    unsigned s = 0;
    #pragma unroll
    for (int j = 0; j < 4; ++j) { int i = i0 + j; if (i < n) s += c[i]; }
    __shared__ unsigned sh[256];
    sh[threadIdx.x] = s; __syncthreads();
    for (int off = 128; off; off >>= 1) {
        if (threadIdx.x < (unsigned)off) sh[threadIdx.x] += sh[threadIdx.x + off];
        __syncthreads();
    }
    if (threadIdx.x == 0) bsum[blockIdx.x] = sh[0];
}

__global__ __launch_bounds__(256)
void scan_p2(unsigned* __restrict__ bsum, int nblk, int* __restrict__ rowptr,
             int Nmax, int n0, int n1)
{
    __shared__ unsigned sh[256];
    int tot = 2 * nblk;
    int t = threadIdx.x;
    unsigned v = (t < tot) ? bsum[t] : 0u;
    sh[t] = v; __syncthreads();
    for (int off = 1; off < 256; off <<= 1) {
        unsigned add = (t >= off) ? sh[t - off] : 0u;
        __syncthreads(); sh[t] += add; __syncthreads();
    }
    unsigned t0 = sh[nblk - 1];
    unsigned tall = sh[255];
    unsigned excl = sh[t] - v;
    if (t < tot) bsum[t] = (t < nblk) ? excl : excl - t0;
    if (t == 0) {
        rowptr[n0] = (int)t0;
        rowptr[(Nmax + 1) + n1] = (int)(tall - t0);
    }
}

__global__ __launch_bounds__(256)
void scan_p3(const unsigned* __restrict__ cnt, const unsigned* __restrict__ bsum,
             int* __restrict__ rowptr, unsigned* __restrict__ cursor,
             int Nmax, int nblk, int n0, int n1)
{
    int ty = blockIdx.x / nblk, b = blockIdx.x % nblk;
    int n = ty ? n1 : n0;
    const unsigned* c = cnt + (size_t)ty * Nmax;
    int* rp = rowptr + (size_t)ty * (Nmax + 1);
    unsigned* cur = cursor + (size_t)ty * Nmax;
    int t = threadIdx.x;
    int i0 = b * 1024 + t * 4;
    unsigned v[4]; unsigned s = 0;
    #pragma unroll
    for (int j = 0; j < 4; ++j) { int i = i0 + j; v[j] = (i < n) ? c[i] : 0u; s += v[j]; }
    __shared__ unsigned sh[256];
    sh[t] = s; __syncthreads();
    for (int off = 1; off < 256; off <<= 1) {
        unsigned add = (t >= off) ? sh[t - off] : 0u;
        __syncthreads(); sh[t] += add; __syncthreads();
    }
    unsigned run = bsum[blockIdx.x] + sh[t] - s;
    #pragma unroll
    for (int j = 0; j < 4; ++j) {
        int i = i0 + j;
        if (i < n) { rp[i] = (int)run; cur[i] = run; }
        run += v[j];
    }
}

__global__ void scatter4(const int* __restrict__ e0, int E0, const int* __restrict__ e1, int E1,
                         const int* __restrict__ e2, int E2, const int* __restrict__ e3, int E3,
                         unsigned* __restrict__ cursor, int Nmax,
                         unsigned* __restrict__ adj0, unsigned* __restrict__ adj1)
{
    int i = blockIdx.x * blockDim.x + threadIdx.x;
    int tot = E0 + E1 + E2 + E3;
    int stride = gridDim.x * blockDim.x;
    for (; i < tot; i += stride) {
        int j = i; const int* e; int E; int dt; unsigned rb;
        if (j < E0) { e = e0; E = E0; dt = 0; rb = 0u; }
        else { j -= E0;
            if (j < E1) { e = e1; E = E1; dt = 1; rb = 0u; }
            else { j -= E1;
                if (j < E2) { e = e2; E = E2; dt = 0; rb = 1u << 24; }
                else { j -= E2; e = e3; E = E3; dt = 1; rb = 1u << 24; }
            }
        }
        int s = e[j], d = e[E + j];
        unsigned pos = atomicAdd(&cursor[(size_t)dt * Nmax + d], 1u);
        (dt ? adj1 : adj0)[pos] = (unsigned)s | rb;
    }
}

// ---- single-pass 2-product MFMA GEMM, 64-row tile, 256 thr ----
template <int ASPLIT, int EPI, int OUT, int NK>
__global__ __launch_bounds__(256)
void mg2p(const void* __restrict__ Ain, const unsigned short* __restrict__ Whi,
          const float* __restrict__ bias,
          const unsigned short* __restrict__ xold, const float* __restrict__ skipp,
          void* __restrict__ Cout, int N)
{
    constexpr int K = NK * 32;
    constexpr int PB = NK * 8192;
    constexpr size_t LSZ = (OUT == 2 && ST_BYTES > PB) ? ST_BYTES : PB;
    __shared__ char ldsraw[LSZ];
    unsigned short* lds = (unsigned short*)ldsraw;
    int t = threadIdx.x;
    constexpr int NCP = PB / (16 * 256);
    #pragma unroll
    for (int i = 0; i < NCP; ++i)
        gload_lds16((const char*)Whi + ((size_t)t + i * 256) * 16,
                    ldsraw + ((size_t)t + i * 256) * 16);
    __syncthreads();

    int w = t >> 6, lane = t & 63;
    int lr = lane & 15, g = lane >> 4;
    int row0 = blockIdx.x * 64;
    int fnb = w * 2;

    f4v acc[4][2];
    #pragma unroll
    for (int i = 0; i < 4; ++i) { acc[i][0] = (f4v)0.f; acc[i][1] = (f4v)0.f; }

    #pragma unroll
    for (int ks = 0; ks < NK; ++ks) {
        s8v ah[4], al[4];
        #pragma unroll
        for (int fm = 0; fm < 4; ++fm) {
            int row = row0 + fm * 16 + lr;
            if (row < N) {
                if (ASPLIT) {
                    const unsigned short* ap = (const unsigned short*)Ain + (size_t)row * 256 + ks * 32 + g * 8;
                    ah[fm] = *(const s8v*)ap;
                    al[fm] = *(const s8v*)(ap + 128);
                } else {
                    const float* ap = (const float*)Ain + (size_t)row * K + ks * 32 + g * 8;
                    float4 p = *(const float4*)ap;
                    float4 q = *(const float4*)(ap + 4);
                    float xv[8] = {p.x, p.y, p.z, p.w, q.x, q.y, q.z, q.w};
                    #pragma unroll
                    for (int j = 0; j < 8; ++j) {
                        unsigned short h = f2bf(xv[j]);
                        ah[fm][j] = (short)h;
                        al[fm][j] = (short)f2bf(xv[j] - bf2f(h));
                    }
                }
            } else { ah[fm] = (s8v)0; al[fm] = (s8v)0; }
        }
        #pragma unroll
        for (int f = 0; f < 2; ++f) {
            size_t co = (size_t)ks * 8192 + (fnb + f) * 1024 + g * 256 + lr * 16;
            s8v b = *(const s8v*)(ldsraw + co);
            #pragma unroll
            for (int fm = 0; fm < 4; ++fm) {
                acc[fm][f] = __builtin_amdgcn_mfma_f32_16x16x32_bf16(ah[fm], b, acc[fm][f], 0, 0, 0);
                acc[fm][f] = __builtin_amdgcn_mfma_f32_16x16x32_bf16(al[fm], b, acc[fm][f], 0, 0, 0);
            }
        }
    }

    float beta = 0.f;
    if (EPI == 2) beta = 1.f / (1.f + __expf(-skipp[0]));
    int rb = g * 4;

    if (OUT == 2) {
        __syncthreads();
        #pragma unroll
        for (int f = 0; f < 2; ++f) {
            int col = (fnb + f) * 16 + lr;
            float bv = bias[col];
            #pragma unroll
            for (int fm = 0; fm < 4; ++fm) {
                #pragma unroll
                for (int j = 0; j < 4; ++j) {
                    int lrow = fm * 16 + rb + j;
                    int row = row0 + lrow;
                    float o = acc[fm][f][j] + bv;
                    if (EPI == 1) o = fmaxf(o, 0.f);
                    if (EPI == 2) {
                        float xo = (row < N) ? (bf2f(xold[(size_t)row * 256 + col]) +
                                                bf2f(xold[(size_t)row * 256 + 128 + col])) : 0.f;
                        o = beta * o + (1.f - beta) * xo;
                    }
                    unsigned short h = f2bf(o);
                    lds[(size_t)lrow * ST_STRIDE + col] = h;
                    lds[(size_t)lrow * ST_STRIDE + 128 + col] = f2bf(o - bf2f(h));
                }
            }
        }
        __syncthreads();
        unsigned short* C = (unsigned short*)Cout;
        #pragma unroll
        for (int it = 0; it < 8; ++it) {
            int d4 = (it * 256 + t) * 4;
            int row = d4 >> 7, c2 = d4 & 127;
            int grow = row0 + row;
            if (grow < N) {
                uint4 v = *(const uint4*)(lds + (size_t)row * ST_STRIDE + c2 * 2);
                *(uint4*)(C + (size_t)grow * 256 + c2 * 2) = v;
            }
        }
    } else {
        float* C = (float*)Cout;
        #pragma unroll
        for (int f = 0; f < 2; ++f) {
            int col = (fnb + f) * 16 + lr;
            float bv = bias[col];
            #pragma unroll
            for (int fm = 0; fm < 4; ++fm) {
                #pragma unroll
                for (int j = 0; j < 4; ++j) {
                    int row = row0 + fm * 16 + rb + j;
                    if (row < N) C[(size_t)row * HIDC + col] = acc[fm][f][j] + bv;
                }
            }
        }
    }
}

// ---- batched dual kv GEMM: 4 jobs (st,dt), 64-row tile, 2-product ----
struct KvArgs {
    const unsigned short* A[4];
    const unsigned short* Wm[4];
    const float* bias[4];
    unsigned short* out[4];
    int N[4];
    int cum[5];
};

__global__ __launch_bounds__(256)
void mgemm_kv4(KvArgs args)
{
    int bid = blockIdx.x;
    int jb = 0;
    while (jb < 3 && bid >= args.cum[jb + 1]) ++jb;
    int lb = bid - args.cum[jb];
    const unsigned short* Ain = args.A[jb];
    const unsigned short* Wkt = args.Wm[jb];
    const unsigned short* Wvt = args.Wm[jb] + 32768;
    const float* bias2 = args.bias[jb];
    unsigned short* kv = args.out[jb];
    int N = args.N[jb];

    __shared__ char ldsraw[65536];
    unsigned short* lds = (unsigned short*)ldsraw;
    int t = threadIdx.x;
    #pragma unroll
    for (int i = 0; i < 8; ++i)
        gload_lds16((const char*)Wkt + ((size_t)t + i * 256) * 16,
                    ldsraw + ((size_t)t + i * 256) * 16);
    #pragma unroll
    for (int i = 0; i < 8; ++i)
        gload_lds16((const char*)Wvt + ((size_t)t + i * 256) * 16,
                    ldsraw + 32768 + ((size_t)t + i * 256) * 16);

    int w = t >> 6, lane = t & 63;
    int lr = lane & 15, g = lane >> 4;
    int row0 = lb * 64;
    int fnb = w * 2;

    s8v ah[4][4], al[4][4];
    #pragma unroll
    for (int fm = 0; fm < 4; ++fm) {
        int row = row0 + fm * 16 + lr;
        #pragma unroll
        for (int ks = 0; ks < 4; ++ks) {
            if (row < N) {
                const unsigned short* ap = Ain + (size_t)row * 256 + ks * 32 + g * 8;
                ah[fm][ks] = *(const s8v*)ap;
                al[fm][ks] = *(const s8v*)(ap + 128);
            } else { ah[fm][ks] = (s8v)0; al[fm][ks] = (s8v)0; }
        }
    }
    __syncthreads();

    f4v acck[4][2], accv[4][2];
    #pragma unroll
    for (int i = 0; i < 4; ++i) {
        acck[i][0] = (f4v)0.f; acck[i][1] = (f4v)0.f;
        accv[i][0] = (f4v)0.f; accv[i][1] = (f4v)0.f;
    }

    #pragma unroll
    for (int ks = 0; ks < 4; ++ks) {
        #pragma unroll
        for (int f = 0; f < 2; ++f) {
            int fn = fnb + f;
            size_t co = (size_t)ks * 8192 + fn * 1024 + g * 256 + lr * 16;
            s8v bk_ = *(const s8v*)(ldsraw + co);
            s8v bv_ = *(const s8v*)(ldsraw + 32768 + co);
            #pragma unroll
            for (int fm = 0; fm < 4; ++fm) {
                acck[fm][f] = __builtin_amdgcn_mfma_f32_16x16x32_bf16(ah[fm][ks], bk_, acck[fm][f], 0, 0, 0);
                acck[fm][f] = __builtin_amdgcn_mfma_f32_16x16x32_bf16(al[fm][ks], bk_, acck[fm][f], 0, 0, 0);
                accv[fm][f] = __builtin_amdgcn_mfma_f32_16x16x32_bf16(ah[fm][ks], bv_, accv[fm][f], 0, 0, 0);
                accv[fm][f] = __builtin_amdgcn_mfma_f32_16x16x32_bf16(al[fm][ks], bv_, accv[fm][f], 0, 0, 0);
            }
        }
    }

    __syncthreads();
    int rb = g * 4;
    #pragma unroll
    for (int f = 0; f < 2; ++f) {
        int fn = fnb + f;
        int col = fn * 16 + lr;
        float bk0 = bias2[col], bv0 = bias2[128 + col];
        #pragma unroll
        for (int fm = 0; fm < 4; ++fm) {
            #pragma unroll
            for (int j = 0; j < 4; ++j) {
                int lrow = fm * 16 + rb + j;
                lds[(size_t)lrow * ST_STRIDE + col] = f2bf(acck[fm][f][j] + bk0);
                lds[(size_t)lrow * ST_STRIDE + 128 + col] = f2bf(accv[fm][f][j] + bv0);
            }
        }
    }
    __syncthreads();
    #pragma unroll
    for (int it = 0; it < 8; ++it) {
        int d4 = (it * 256 + t) * 4;
        int row = d4 >> 7, c2 = d4 & 127;
        int grow = row0 + row;
        if (grow < N) {
            uint4 v = *(const uint4*)(lds + (size_t)row * ST_STRIDE + c2 * 2);
            *(uint4*)(kv + (size_t)grow * 256 + c2 * 2) = v;
        }
    }
}

// ---- batched q GEMM: 2 jobs, 64-row tile, 2-product, bf16 out (padded 512B rows) ----
struct QArgs {
    const unsigned short* A[2];
    const unsigned short* W[2];
    const float* bias[2];
    unsigned short* out[2];   // bf16 q rows at stride 256 ushorts (first 128 used)
    int N[2];
    int cum[3];
};

__global__ __launch_bounds__(256)
void mgemm_q2(QArgs args)
{
    int bid = blockIdx.x;
    int jb = (bid >= args.cum[1]) ? 1 : 0;
    int lb = bid - args.cum[jb];
    const unsigned short* Ain = args.A[jb];
    const unsigned short* Whi = args.W[jb];
    const float* bias = args.bias[jb];
    unsigned short* Cout = args.out[jb];
    int N = args.N[jb];

    __shared__ char ldsraw[ST_BYTES];
    unsigned short* lds = (unsigned short*)ldsraw;
    int t = threadIdx.x;
    #pragma unroll
    for (int i = 0; i < 8; ++i)
        gload_lds16((const char*)Whi + ((size_t)t + i * 256) * 16,
                    ldsraw + ((size_t)t + i * 256) * 16);
    __syncthreads();

    int w = t >> 6, lane = t & 63;
    int lr = lane & 15, g = lane >> 4;
    int row0 = lb * 64;
    int fnb = w * 2;

    f4v acc[4][2];
    #pragma unroll
    for (int i = 0; i < 4; ++i) { acc[i][0] = (f4v)0.f; acc[i][1] = (f4v)0.f; }

    #pragma unroll
    for (int ks = 0; ks < 4; ++ks) {
        s8v ah[4], al[4];
        #pragma unroll
        for (int fm = 0; fm < 4; ++fm) {
            int row = row0 + fm * 16 + lr;
            if (row < N) {
                const unsigned short* ap = Ain + (size_t)row * 256 + ks * 32 + g * 8;
                ah[fm] = *(const s8v*)ap;
                al[fm] = *(const s8v*)(ap + 128);
            } else { ah[fm] = (s8v)0; al[fm] = (s8v)0; }
        }
        #pragma unroll
        for (int f = 0; f < 2; ++f) {
            size_t co = (size_t)ks * 8192 + (fnb + f) * 1024 + g * 256 + lr * 16;
            s8v b = *(const s8v*)(ldsraw + co);
            #pragma unroll
            for (int fm = 0; fm < 4; ++fm) {
                acc[fm][f] = __builtin_amdgcn_mfma_f32_16x16x32_bf16(ah[fm], b, acc[fm][f], 0, 0, 0);
                acc[fm][f] = __builtin_amdgcn_mfma_f32_16x16x32_bf16(al[fm], b, acc[fm][f], 0, 0, 0);
            }
        }
    }

    int rb = g * 4;
    __syncthreads();   // weights dead; reuse as staging
    #pragma unroll
    for (int f = 0; f < 2; ++f) {
        int col = (fnb + f) * 16 + lr;
        float bv = bias[col];
        #pragma unroll
        for (int fm = 0; fm < 4; ++fm) {
            #pragma unroll
            for (int j = 0; j < 4; ++j) {
                int lrow = fm * 16 + rb + j;
                lds[(size_t)lrow * ST_STRIDE + col] = f2bf(acc[fm][f][j] + bv);
            }
        }
    }
    __syncthreads();
    // flush 64 rows x 256 B coalesced; dest rows padded to 512 B stride
    #pragma unroll
    for (int it = 0; it < 4; ++it) {
        int idx = it * 256 + t;
        int row = idx >> 4, u = idx & 15;
        int grow = row0 + row;
        if (grow < N) {
            uint4 v = *(const uint4*)(lds + (size_t)row * ST_STRIDE + u * 8);
            *(uint4*)(Cout + (size_t)grow * 256 + u * 8) = v;
        }
    }
}

// ---- batched outproj GEMM: 2 jobs, 64-row tile, 2-product, skip-blend, in-place ----
struct OArgs {
    const unsigned short* A[2];
    const unsigned short* W[2];
    const float* bias[2];
    const float* skipp[2];
    unsigned short* x[2];
    int N[2];
    int cum[3];
};

__global__ __launch_bounds__(256)
void mgemm_op2(OArgs args)
{
    int bid = blockIdx.x;
    int jb = (bid >= args.cum[1]) ? 1 : 0;
    int lb = bid - args.cum[jb];
    const unsigned short* Ain = args.A[jb];
    const unsigned short* Whi = args.W[jb];
    const float* bias = args.bias[jb];
    const unsigned short* xold = args.x[jb];
    unsigned short* Cout = args.x[jb];
    float beta = 1.f / (1.f + __expf(-args.skipp[jb][0]));
    int N = args.N[jb];

    __shared__ char ldsraw[ST_BYTES];
    unsigned short* lds = (unsigned short*)ldsraw;
    int t = threadIdx.x;
    #pragma unroll
    for (int i = 0; i < 8; ++i)
        gload_lds16((const char*)Whi + ((size_t)t + i * 256) * 16,
                    ldsraw + ((size_t)t + i * 256) * 16);
    __syncthreads();

    int w = t >> 6, lane = t & 63;
    int lr = lane & 15, g = lane >> 4;
    int row0 = lb * 64;
    int fnb = w * 2;

    f4v acc[4][2];
    #pragma unroll
    for (int i = 0; i < 4; ++i) { acc[i][0] = (f4v)0.f; acc[i][1] = (f4v)0.f; }

    #pragma unroll
    for (int ks = 0; ks < 4; ++ks) {
        s8v ah[4], al[4];
        #pragma unroll
        for (int fm = 0; fm < 4; ++fm) {
            int row = row0 + fm * 16 + lr;
            if (row < N) {
                const unsigned short* ap = Ain + (size_t)row * 256 + ks * 32 + g * 8;
                ah[fm] = *(const s8v*)ap;
                al[fm] = *(const s8v*)(ap + 128);
            } else { ah[fm] = (s8v)0; al[fm] = (s8v)0; }
        }
        #pragma unroll
        for (int f = 0; f < 2; ++f) {
            size_t co = (size_t)ks * 8192 + (fnb + f) * 1024 + g * 256 + lr * 16;
            s8v b = *(const s8v*)(ldsraw + co);
            #pragma unroll
            for (int fm = 0; fm < 4; ++fm) {
                acc[fm][f] = __builtin_amdgcn_mfma_f32_16x16x32_bf16(ah[fm], b, acc[fm][f], 0, 0, 0);
                acc[fm][f] = __builtin_amdgcn_mfma_f32_16x16x32_bf16(al[fm], b, acc[fm][f], 0, 0, 0);
            }
        }
    }

    int rb = g * 4;
    __syncthreads();
    #pragma unroll
    for (int f = 0; f < 2; ++f) {
        int col = (fnb + f) * 16 + lr;
        float bv = bias[col];
        #pragma unroll
        for (int fm = 0; fm < 4; ++fm) {
            #pragma unroll
            for (int j = 0; j < 4; ++j) {
                int lrow = fm * 16 + rb + j;
                int row = row0 + lrow;
                float o = acc[fm][f][j] + bv;
                float xo = (row < N) ? (bf2f(xold[(size_t)row * 256 + col]) +
                                        bf2f(xold[(size_t)row * 256 + 128 + col])) : 0.f;
                o = beta * o + (1.f - beta) * xo;
                unsigned short h = f2bf(o);
                lds[(size_t)lrow * ST_STRIDE + col] = h;
                lds[(size_t)lrow * ST_STRIDE + 128 + col] = f2bf(o - bf2f(h));
            }
        }
    }
    __syncthreads();
    #pragma unroll
    for (int it = 0; it < 8; ++it) {
        int d4 = (it * 256 + t) * 4;
        int row = d4 >> 7, c2 = d4 & 127;
        int grow = row0 + row;
        if (grow < N) {
            uint4 v = *(const uint4*)(lds + (size_t)row * ST_STRIDE + c2 * 2);
            *(uint4*)(Cout + (size_t)grow * 256 + c2 * 2) = v;
        }
    }
}

// ---- batched fused aggregation: 2 jobs (dt 0/1); wave/node, single-exp online SM ----
// Q is bf16 at stride 256 ushorts (padded); msgs written in place over same rows.
#define EDGE_STEP(IDX, M, S, AX, AY)                                               \
    {                                                                              \
        unsigned ent = adj[IDX];                                                   \
        int src = (int)(ent & 0xFFFFFFu);                                          \
        const unsigned short* kv = (ent >> 24) ? kvB : kvA;                        \
        float sp = (ent >> 24) ? spB : spA;                                        \
        ushort2 kraw = *(const ushort2*)(kv + (size_t)src * 256 + lane * 2);       \
        ushort2 vraw = *(const ushort2*)(kv + (size_t)src * 256 + 128 + lane * 2); \
        float p = bf2f(kraw.x) * qvx + bf2f(kraw.y) * qvy;                         \
        p += __shfl_xor(p, 1, 8);                                                  \
        p += __shfl_xor(p, 2, 8);                                                  \
        p += __shfl_xor(p, 4, 8);                                                  \
        float a = p * sp;                                                          \
        float d = a - M;                                                           \
        float e = __expf(-fabsf(d));                                               \
        bool nm = d > 0.f;                                                         \
        float sc = nm ? e : 1.f;                                                   \
        float pw = nm ? 1.f : e;                                                   \
        S = S * sc + pw;                                                           \
        AX = AX * sc + pw * bf2f(vraw.x);                                          \
        AY = AY * sc + pw * bf2f(vraw.y);                                          \
        M = nm ? a : M;                                                            \
    }

struct AArgs {
    const unsigned short* Q[2];
    const unsigned short* kvA_[2];
    const unsigned short* kvB_[2];
    const int* rowptr[2];
    const unsigned* adjp[2];
    const float* prelA_[2];
    const float* prelB_[2];
    unsigned short* out[2];   // aliases Q buffer (same rows, in-place)
    int N[2];
    int cum[3];
};

__global__ __launch_bounds__(256)
void agg2(AArgs args, float scale)
{
    int bid = blockIdx.x;
    int jb = (bid >= args.cum[1]) ? 1 : 0;
    int lb = bid - args.cum[jb];
    const unsigned short* Q = args.Q[jb];
    const unsigned short* kvA = args.kvA_[jb];
    const unsigned short* kvB = args.kvB_[jb];
    const int* rowptr = args.rowptr[jb];
    const unsigned* adj = args.adjp[jb];
    unsigned short* msgs = args.out[jb];
    int N = args.N[jb];

    int node = lb * 4 + (threadIdx.x >> 6);
    if (node >= N) return;
    int lane = threadIdx.x & 63;
    int h = lane >> 3;
    float spA = args.prelA_[jb][h] * scale, spB = args.prelB_[jb][h] * scale;
    ushort2 qr = *(const ushort2*)(Q + (size_t)node * 256 + lane * 2);
    float qvx = bf2f(qr.x), qvy = bf2f(qr.y);
    int beg = rowptr[node], end = rowptr[node + 1];

    float m0 = MNEG, s0 = 0.f, ax0 = 0.f, ay0 = 0.f;
    float m1 = MNEG, s1 = 0.f, ax1 = 0.f, ay1 = 0.f;
    int i = beg;
    for (; i + 1 < end; i += 2) {
        EDGE_STEP(i,     m0, s0, ax0, ay0);
        EDGE_STEP(i + 1, m1, s1, ax1, ay1);
    }
    if (i < end) EDGE_STEP(i, m0, s0, ax0, ay0);

    float ox = 0.f, oy = 0.f;
    if (end > beg) {
        float mn = fmaxf(m0, m1);
        float c0 = __expf(m0 - mn), c1 = __expf(m1 - mn);
        float s = s0 * c0 + s1 * c1;
        float inv = 1.f / fmaxf(s, 1e-16f);
        ox = (ax0 * c0 + ax1 * c1) * inv;
        oy = (ay0 * c0 + ay1 * c1) * inv;
    }
    ox = gelu_f(ox); oy = gelu_f(oy);
    unsigned short hx = f2bf(ox), hy = f2bf(oy);
    size_t base = (size_t)node * 256 + lane * 2;
    ushort2 hi2; hi2.x = hx; hi2.y = hy;
    ushort2 lo2; lo2.x = f2bf(ox - bf2f(hx)); lo2.y = f2bf(oy - bf2f(hy));
    *(ushort2*)(msgs + base) = hi2;
    *(ushort2*)(msgs + base + 128) = lo2;
}

// ---- classifier: one wave per row, x split-bf16 ----
__global__ __launch_bounds__(256)
void cls_kernel(const unsigned short* __restrict__ X, const float* __restrict__ Wc,
                const float* __restrict__ bc, float* __restrict__ out, int N)
{
    int row = blockIdx.x * 4 + (threadIdx.x >> 6);
    if (row >= N) return;
    int lane = threadIdx.x & 63;
    const unsigned short* xr = X + (size_t)row * 256 + lane * 2;
    float x0 = bf2f(xr[0]) + bf2f(xr[128]);
    float x1 = bf2f(xr[1]) + bf2f(xr[129]);
    float p0, p1, p2, p3;
    {
        float2 w0 = *(const float2*)(Wc + 0 * HIDC + lane * 2);
        float2 w1 = *(const float2*)(Wc + 1 * HIDC + lane * 2);
        float2 w2 = *(const float2*)(Wc + 2 * HIDC + lane * 2);
        float2 w3 = *(const float2*)(Wc + 3 * HIDC + lane * 2);
        p0 = x0 * w0.x + x1 * w0.y;
        p1 = x0 * w1.x + x1 * w1.y;
        p2 = x0 * w2.x + x1 * w2.y;
        p3 = x0 * w3.x + x1 * w3.y;
    }
    #pragma unroll
    for (int off = 32; off; off >>= 1) {
        p0 += __shfl_xor(p0, off);
        p1 += __shfl_xor(p1, off);
        p2 += __shfl_xor(p2, off);
        p3 += __shfl_xor(p3, off);
    }
    if (lane < 4) {
        float v = (lane == 0) ? p0 : (lane == 1) ? p1 : (lane == 2) ? p2 : p3;
        out[(size_t)row * NCLS + lane] = v + bc[lane];
    }
}

extern "C" void kernel_launch(void* const* d_in, const int* in_sizes, int n_in,
                              void* d_out, int out_size, void* d_ws, size_t ws_size,
                              hipStream_t stream)
{
    const float* x_a    = (const float*)d_in[0];
    const float* x_b    = (const float*)d_in[1];
    const float* lin_W_a= (const float*)d_in[2];
    const float* lin_b_a= (const float*)d_in[3];
    const float* lin_W_b= (const float*)d_in[4];
    const float* lin_b_b= (const float*)d_in[5];
    const float* Wk     = (const float*)d_in[6];
    const float* bk     = (const float*)d_in[7];
    const float* Wq     = (const float*)d_in[8];
    const float* bq     = (const float*)d_in[9];
    const float* Wv     = (const float*)d_in[10];
    const float* bv     = (const float*)d_in[11];
    const float* arel   = (const float*)d_in[12];
    const float* mrel   = (const float*)d_in[13];
    const float* prel   = (const float*)d_in[14];
    const float* Wa     = (const float*)d_in[15];
    const float* ba     = (const float*)d_in[16];
    const float* skip   = (const float*)d_in[17];
    const float* Wcls   = (const float*)d_in[18];
    const float* bcls   = (const float*)d_in[19];
    const int* eptr[4] = {(const int*)d_in[20], (const int*)d_in[21],
                          (const int*)d_in[22], (const int*)d_in[23]};
    int Ee[4] = {in_sizes[20] / 2, in_sizes[21] / 2, in_sizes[22] / 2, in_sizes[23] / 2};

    int Ka = in_sizes[2] / HIDC;     // 64
    int Kb = in_sizes[4] / HIDC;     // 32
    int Na = in_sizes[0] / Ka;
    int Nb = in_sizes[1] / Kb;
    int Nn[2] = {Na, Nb};
    int Nmax = Na > Nb ? Na : Nb;

    // ---- workspace layout (~212 MB) ----
    char* base = (char*)d_ws;
    unsigned short* xs[2];
    xs[0] = (unsigned short*)base; base += (size_t)Na * 256 * 2;
    xs[1] = (unsigned short*)base; base += (size_t)Nb * 256 * 2;
    unsigned short* qb[2];   // bf16 q rows (512B stride); after agg: split-bf16 msgs
    qb[0] = (unsigned short*)base; base += (size_t)Na * 256 * 2;
    qb[1] = (unsigned short*)base; base += (size_t)Nb * 256 * 2;
    unsigned short* kvb[2][2];
    for (int s = 0; s < 2; ++s)
        for (int d = 0; d < 2; ++d) { kvb[s][d] = (unsigned short*)base; base += (size_t)Nn[s] * 256 * 2; }
    float* Wt = (float*)base; base += (size_t)16 * HIDC * HIDC * 4;
    float* bt = (float*)base; base += (size_t)16 * HIDC * 4;
    size_t nW2 = (size_t)2 * (Ka + Kb) * 128 + (size_t)24 * 32768;  // ushorts
    unsigned short* W2 = (unsigned short*)base; base += nW2 * 2;
    unsigned* cnt = (unsigned*)base; base += (size_t)2 * Nmax * 4;
    unsigned* cursor = (unsigned*)base; base += (size_t)2 * Nmax * 4;
    unsigned* bsum = (unsigned*)base; base += 256 * 4;
    int* rowptr = (int*)base; base += (size_t)2 * (Nmax + 1) * 4;
    unsigned* adj0 = (unsigned*)base; base += (size_t)(Ee[0] + Ee[2]) * 4;
    unsigned* adj1 = (unsigned*)base; base += (size_t)(Ee[1] + Ee[3]) * 4;

    // W2 mat offsets (ushorts)
    size_t off_lina = 0;
    size_t off_linb = (size_t)2 * Ka * 128;
    size_t base128  = (size_t)2 * (Ka + Kb) * 128;
    auto offKT = [&](int l, int st, int dt) { return base128 + (size_t)(l * 8 + (st * 2 + dt) * 2) * 32768; };
    auto offQ  = [&](int l, int tt) { return base128 + (size_t)(16 + l * 2 + tt) * 32768; };
    auto offA  = [&](int l, int tt) { return base128 + (size_t)(20 + l * 2 + tt) * 32768; };

    // ---- weight prep ----
    fold_all<<<16, 128, 0, stream>>>(Wk, bk, Wv, bv, arel, mrel, Wt, bt);
    int nwblk = (Ka >> 5) + (Kb >> 5) + 24 * 4;
    wsplit<<<nwblk, 128, 0, stream>>>(lin_W_a, lin_W_b, Wq, Wa, Wt, W2, Ka, Kb);

    // ---- CSR build ----
    int nblk = (Nmax + 1023) / 1024;
    zero_u32<<<512, 256, 0, stream>>>(cnt, (long)2 * Nmax);
    hist4<<<1024, 256, 0, stream>>>(eptr[0] + Ee[0], Ee[0], eptr[1] + Ee[1], Ee[1],
                                    eptr[2] + Ee[2], Ee[2], eptr[3] + Ee[3], Ee[3],
                                    cnt, Nmax);
    scan_p1<<<2 * nblk, 256, 0, stream>>>(cnt, bsum, Nmax, nblk, Na, Nb);
    scan_p2<<<1, 256, 0, stream>>>(bsum, nblk, rowptr, Nmax, Na, Nb);
    scan_p3<<<2 * nblk, 256, 0, stream>>>(cnt, bsum, rowptr, cursor, Nmax, nblk, Na, Nb);
    scatter4<<<1024, 256, 0, stream>>>(eptr[0], Ee[0], eptr[1], Ee[1],
                                       eptr[2], Ee[2], eptr[3], Ee[3],
                                       cursor, Nmax, adj0, adj1);

    // ---- input projections + ReLU -> split-bf16 x ----
    int gn64[2] = {(Na + 63) / 64, (Nb + 63) / 64};
    mg2p<0, 1, 2, 2><<<gn64[0], 256, 0, stream>>>(x_a, W2 + off_lina, lin_b_a,
                                                  nullptr, nullptr, xs[0], Na);
    mg2p<0, 1, 2, 1><<<gn64[1], 256, 0, stream>>>(x_b, W2 + off_linb, lin_b_b,
                                                  nullptr, nullptr, xs[1], Nb);

    const float scale = 0.25f;   // 1/sqrt(16)
    int ganode[2] = {(Na + 3) / 4, (Nb + 3) / 4};

    for (int l = 0; l < 2; ++l) {
        KvArgs ka;
        int cum = 0;
        for (int j = 0; j < 4; ++j) {
            int st = j >> 1, dt = j & 1;
            int bid = l * 8 + (st * 2 + dt) * 2;
            ka.A[j] = xs[st];
            ka.Wm[j] = W2 + offKT(l, st, dt);
            ka.bias[j] = bt + (size_t)bid * HIDC;
            ka.out[j] = kvb[st][dt];
            ka.N[j] = Nn[st];
            ka.cum[j] = cum;
            cum += gn64[st];
        }
        ka.cum[4] = cum;
        mgemm_kv4<<<cum, 256, 0, stream>>>(ka);

        QArgs qa;
        for (int j = 0; j < 2; ++j) {
            qa.A[j] = xs[j];
            qa.W[j] = W2 + offQ(l, j);
            qa.bias[j] = bq + (l * 2 + j) * HIDC;
            qa.out[j] = qb[j];
            qa.N[j] = Nn[j];
        }
        qa.cum[0] = 0; qa.cum[1] = gn64[0]; qa.cum[2] = gn64[0] + gn64[1];
        mgemm_q2<<<qa.cum[2], 256, 0, stream>>>(qa);

        AArgs aa;
        aa.Q[0] = qb[0]; aa.Q[1] = qb[1];
        aa.kvA_[0] = kvb[0][0]; aa.kvB_[0] = kvb[1][0];
        aa.kvA_[1] = kvb[0][1]; aa.kvB_[1] = kvb[1][1];
        aa.rowptr[0] = rowptr; aa.rowptr[1] = rowptr + (Nmax + 1);
        aa.adjp[0] = adj0; aa.adjp[1] = adj1;
        aa.prelA_[0] = prel + (l * 4 + 0) * NH; aa.prelB_[0] = prel + (l * 4 + 2) * NH;
        aa.prelA_[1] = prel + (l * 4 + 1) * NH; aa.prelB_[1] = prel + (l * 4 + 3) * NH;
        aa.out[0] = qb[0]; aa.out[1] = qb[1];
        aa.N[0] = Nn[0]; aa.N[1] = Nn[1];
        aa.cum[0] = 0; aa.cum[1] = ganode[0]; aa.cum[2] = ganode[0] + ganode[1];
        agg2<<<aa.cum[2], 256, 0, stream>>>(aa, scale);

        OArgs oa;
        for (int j = 0; j < 2; ++j) {
            oa.A[j] = qb[j];
            oa.W[j] = W2 + offA(l, j);
            oa.bias[j] = ba + (l * 2 + j) * HIDC;
            oa.skipp[j] = skip + (l * 2 + j);
            oa.x[j] = xs[j];
            oa.N[j] = Nn[j];
        }
        oa.cum[0] = 0; oa.cum[1] = gn64[0]; oa.cum[2] = gn64[0] + gn64[1];
        mgemm_op2<<<oa.cum[2], 256, 0, stream>>>(oa);
    }

    cls_kernel<<<(Na + 3) / 4, 256, 0, stream>>>(xs[0], Wcls, bcls, (float*)d_out, Na);
}